// Round 12
// baseline (858.305 us; speedup 1.0000x reference)
//
#include <hip/hip_runtime.h>
#include <math.h>

#define N_NODES 50000
#define N_EDGES 400000
#define IN_F 128
#define HC 176
#define NGRAPH 64

typedef _Float16 half8 __attribute__((ext_vector_type(8)));
typedef float floatx4 __attribute__((ext_vector_type(4)));

// =====================================================================
// Packed split-fp16 weights in MFMA B-fragment order.
// For each matrix: [kc][ct][s(hi/lo)][lane][j]  (halves)
//   value = W[kc*32 + (lane>>4)*8 + j][ct*16 + (lane&15)]  (0 if k >= K)
// Mat order: pre(nkc=4) | 4 layers x {Wl,Wr,Wres}(nkc=6) | c5Wl,c5Wr(nkc=6)
// =====================================================================
#define PREH 45056   // 4*11*2*512 halves
#define MATH 67584   // 6*11*2*512 halves
#define TOT_PAIRS 495616  // 22528 + 14*33792
#define KCBYTES 22528     // bytes per kc chunk (11*2*512*2)
#define GX8 49            // row-tile groups of 8 (49*8=392 >= 391 tiles)

__global__ void prep_kernel(const float* __restrict__ Wpre,
                            const float* __restrict__ cWl, const float* __restrict__ cWr,
                            const float* __restrict__ cWres,
                            const float* __restrict__ c5Wl, const float* __restrict__ c5Wr,
                            _Float16* __restrict__ wp) {
  int gid = blockIdx.x * 256 + threadIdx.x;
  if (gid >= TOT_PAIRS) return;
  int mat, idx;
  if (gid < 22528) { mat = 0; idx = gid; }
  else { int g = gid - 22528; mat = 1 + g / 33792; idx = g % 33792; }
  int kc = idx / 5632;
  int rem = idx - kc * 5632;
  int ct = rem / 512;
  int li = rem - ct * 512;
  int lane = li >> 3, j = li & 7;
  int k = kc * 32 + ((lane >> 4) << 3) + j;
  int col = ct * 16 + (lane & 15);
  const float* src; int Ksrc; size_t base;
  if (mat == 0) { src = Wpre; Ksrc = 128; base = 0; }
  else if (mat <= 12) {
    int lm = mat - 1; int layer = lm / 3; int sub = lm - layer * 3;
    const float* s = (sub == 0) ? cWl : (sub == 1) ? cWr : cWres;
    src = s + (size_t)layer * HC * HC; Ksrc = HC;
    base = PREH + (size_t)lm * MATH;
  } else {
    src = (mat == 13) ? c5Wl : c5Wr; Ksrc = HC;
    base = PREH + (size_t)12 * MATH + (size_t)(mat - 13) * MATH;
  }
  float v = (k < Ksrc) ? src[(size_t)k * HC + col] : 0.0f;
  _Float16 h = (_Float16)v;
  _Float16 l = (_Float16)(v - (float)h);
  size_t o = base + (size_t)(kc * 11 + ct) * 1024 + li;
  wp[o] = h;
  wp[o + 512] = l;
}

// =====================================================================
// Split-fp16 MFMA GEMM with block-level LDS staging of B (R7 structure)
// + XCD-aware block swizzle (R8): blocks sharing the same A row-tile but
// different mat have blockIdx.x differing by 8 -> same XCD.
// grid.x = GX8 * nmat * 8.
// =====================================================================
__global__ __launch_bounds__(256, 2) void gemm_mfma(
    const float* __restrict__ A, int M, int K, int nkc, int nmat,
    const _Float16* __restrict__ Wp, int matStride,
    const float* __restrict__ scsh, const int* __restrict__ batch,
    const float* __restrict__ bias0, const float* __restrict__ bias1,
    const float* __restrict__ bias2,
    float* __restrict__ out0, float* __restrict__ out1, float* __restrict__ out2) {
  __shared__ __align__(16) char smem[2 * KCBYTES];
  const int b = blockIdx.x;
  const int grp = b >> 3, sub = b & 7;
  const int mat = grp % nmat;
  const int tile = ((grp / nmat) << 3) | sub;
  if (tile * 128 >= M) return;
  const _Float16* W = Wp + (size_t)mat * matStride;
  float* outp = (mat == 0) ? out0 : (mat == 1) ? out1 : out2;
  const float* bias = (mat == 0) ? bias0 : (mat == 1) ? bias1 : bias2;
  const int tid = threadIdx.x;
  const int lane = tid & 63;
  const int wv = tid >> 6;
  const int m16 = lane & 15, quad = lane >> 4;
  const int kb = quad << 3;
  const int rowBase = tile * 128 + wv * 32;
  const int rA0 = min(rowBase + m16, M - 1);
  const int rA1 = min(rowBase + 16 + m16, M - 1);
  const float* ap0 = A + (size_t)rA0 * K + kb;
  const float* ap1 = A + (size_t)rA1 * K + kb;
  const float* sc0 = nullptr; const float* sh0 = nullptr;
  const float* sc1 = nullptr; const float* sh1 = nullptr;
  if (scsh) {
    int g0 = batch[rA0], g1 = batch[rA1];
    sc0 = scsh + (size_t)g0 * HC + kb;
    sh0 = scsh + (size_t)(NGRAPH + g0) * HC + kb;
    sc1 = scsh + (size_t)g1 * HC + kb;
    sh1 = scsh + (size_t)(NGRAPH + g1) * HC + kb;
  }

  auto stage = [&](int kc, int buf) {
    const char* src = (const char*)W + (size_t)kc * KCBYTES;
    char* dst = smem + buf * KCBYTES;
#pragma unroll
    for (int i = 0; i < 6; i++) {
      int idx = wv * 6 + i;
      if (idx < 22) {
        __builtin_amdgcn_global_load_lds(
            (const __attribute__((address_space(1))) unsigned int*)(src + idx * 1024 + lane * 16),
            (__attribute__((address_space(3))) unsigned int*)(dst + idx * 1024),
            16, 0, 0);
      }
    }
  };

  floatx4 acc0[11], acc1[11];
#pragma unroll
  for (int ct = 0; ct < 11; ct++)
#pragma unroll
    for (int r = 0; r < 4; r++) { acc0[ct][r] = 0.0f; acc1[ct][r] = 0.0f; }

  stage(0, 0);

  for (int kc = 0; kc < nkc; kc++) {
    const int buf = kc & 1;
    __syncthreads();
    if (kc + 1 < nkc) stage(kc + 1, 1 - buf);

    const int koff = kc << 5;
    float va0[8], va1[8];
    if (koff + kb + 8 <= K) {
      float4 u0 = *(const float4*)(ap0 + koff);
      float4 u1 = *(const float4*)(ap0 + koff + 4);
      float4 w0 = *(const float4*)(ap1 + koff);
      float4 w1 = *(const float4*)(ap1 + koff + 4);
      va0[0] = u0.x; va0[1] = u0.y; va0[2] = u0.z; va0[3] = u0.w;
      va0[4] = u1.x; va0[5] = u1.y; va0[6] = u1.z; va0[7] = u1.w;
      va1[0] = w0.x; va1[1] = w0.y; va1[2] = w0.z; va1[3] = w0.w;
      va1[4] = w1.x; va1[5] = w1.y; va1[6] = w1.z; va1[7] = w1.w;
      if (scsh) {
        float s0[8], h0[8], s1[8], h1[8];
        float4 t;
        t = *(const float4*)(sc0 + koff);     s0[0]=t.x; s0[1]=t.y; s0[2]=t.z; s0[3]=t.w;
        t = *(const float4*)(sc0 + koff + 4); s0[4]=t.x; s0[5]=t.y; s0[6]=t.z; s0[7]=t.w;
        t = *(const float4*)(sh0 + koff);     h0[0]=t.x; h0[1]=t.y; h0[2]=t.z; h0[3]=t.w;
        t = *(const float4*)(sh0 + koff + 4); h0[4]=t.x; h0[5]=t.y; h0[6]=t.z; h0[7]=t.w;
        t = *(const float4*)(sc1 + koff);     s1[0]=t.x; s1[1]=t.y; s1[2]=t.z; s1[3]=t.w;
        t = *(const float4*)(sc1 + koff + 4); s1[4]=t.x; s1[5]=t.y; s1[6]=t.z; s1[7]=t.w;
        t = *(const float4*)(sh1 + koff);     h1[0]=t.x; h1[1]=t.y; h1[2]=t.z; h1[3]=t.w;
        t = *(const float4*)(sh1 + koff + 4); h1[4]=t.x; h1[5]=t.y; h1[6]=t.z; h1[7]=t.w;
#pragma unroll
        for (int j = 0; j < 8; j++) {
          va0[j] = fmaxf(fmaf(va0[j], s0[j], h0[j]), 0.0f);
          va1[j] = fmaxf(fmaf(va1[j], s1[j], h1[j]), 0.0f);
        }
      }
    } else {
#pragma unroll
      for (int j = 0; j < 8; j++) { va0[j] = 0.0f; va1[j] = 0.0f; }
    }
    half8 ah0, al0, ah1, al1;
#pragma unroll
    for (int j = 0; j < 8; j++) {
      _Float16 h = (_Float16)va0[j];
      ah0[j] = h; al0[j] = (_Float16)(va0[j] - (float)h);
      _Float16 g = (_Float16)va1[j];
      ah1[j] = g; al1[j] = (_Float16)(va1[j] - (float)g);
    }
    const char* bbase = smem + buf * KCBYTES + lane * 16;
#pragma unroll
    for (int ct = 0; ct < 11; ct++) {
      half8 bh = *(const half8*)(bbase + ct * 2048);
      half8 bl = *(const half8*)(bbase + ct * 2048 + 1024);
      acc0[ct] = __builtin_amdgcn_mfma_f32_16x16x32_f16(ah0, bh, acc0[ct], 0, 0, 0);
      acc1[ct] = __builtin_amdgcn_mfma_f32_16x16x32_f16(ah1, bh, acc1[ct], 0, 0, 0);
      acc0[ct] = __builtin_amdgcn_mfma_f32_16x16x32_f16(al0, bh, acc0[ct], 0, 0, 0);
      acc1[ct] = __builtin_amdgcn_mfma_f32_16x16x32_f16(al1, bh, acc1[ct], 0, 0, 0);
      acc0[ct] = __builtin_amdgcn_mfma_f32_16x16x32_f16(ah0, bl, acc0[ct], 0, 0, 0);
      acc1[ct] = __builtin_amdgcn_mfma_f32_16x16x32_f16(ah1, bl, acc1[ct], 0, 0, 0);
    }
  }

  float bv[11];
#pragma unroll
  for (int ct = 0; ct < 11; ct++) bv[ct] = bias ? bias[ct * 16 + m16] : 0.0f;
#pragma unroll
  for (int r = 0; r < 4; r++) {
    int row0 = rowBase + (quad << 2) + r;
    if (row0 < M) {
      float* op = outp + (size_t)row0 * HC + m16;
#pragma unroll
      for (int ct = 0; ct < 11; ct++) op[ct * 16] = acc0[ct][r] + bv[ct];
    }
    int row1 = row0 + 16;
    if (row1 < M) {
      float* op = outp + (size_t)row1 * HC + m16;
#pragma unroll
      for (int ct = 0; ct < 11; ct++) op[ct * 16] = acc1[ct][r] + bv[ct];
    }
  }
}

// =====================================================================
// GraphNorm stats, vectorized: 4 waves/block, each wave owns a 64-node
// range; lane L<44 accumulates features 4L..4L+3 via float4 (704 B
// contiguous per wave-read). Flush on graph change (batch sorted) ->
// ~550k atomics total (vs 4.4M in the R11 fused scheme that cost 25us).
// =====================================================================
__global__ __launch_bounds__(256) void gn_stats_kernel(const float* __restrict__ h,
                                                       const int* __restrict__ batch,
                                                       float* __restrict__ stats) {
  int t = threadIdx.x;
  int wv = t >> 6, lane = t & 63;
  if (lane >= 44) return;
  int n0 = (blockIdx.x * 4 + wv) * 64;
  if (n0 >= N_NODES) return;
  int n1 = min(n0 + 64, N_NODES);
  int f4 = lane * 4;
  float4 s = make_float4(0.f, 0.f, 0.f, 0.f);
  float4 ss = make_float4(0.f, 0.f, 0.f, 0.f);
  int gcur = batch[n0];
  for (int n = n0; n < n1; n++) {
    int g = batch[n];
    if (g != gcur) {
      float* sp = stats + (size_t)gcur * HC + f4;
      float* qp = stats + (size_t)(NGRAPH + gcur) * HC + f4;
      atomicAdd(sp + 0, s.x); atomicAdd(sp + 1, s.y);
      atomicAdd(sp + 2, s.z); atomicAdd(sp + 3, s.w);
      atomicAdd(qp + 0, ss.x); atomicAdd(qp + 1, ss.y);
      atomicAdd(qp + 2, ss.z); atomicAdd(qp + 3, ss.w);
      s = make_float4(0.f, 0.f, 0.f, 0.f);
      ss = make_float4(0.f, 0.f, 0.f, 0.f);
      gcur = g;
    }
    float4 v = *(const float4*)(h + (size_t)n * HC + f4);
    s.x += v.x; s.y += v.y; s.z += v.z; s.w += v.w;
    ss.x = fmaf(v.x, v.x, ss.x); ss.y = fmaf(v.y, v.y, ss.y);
    ss.z = fmaf(v.z, v.z, ss.z); ss.w = fmaf(v.w, v.w, ss.w);
  }
  float* sp = stats + (size_t)gcur * HC + f4;
  float* qp = stats + (size_t)(NGRAPH + gcur) * HC + f4;
  atomicAdd(sp + 0, s.x); atomicAdd(sp + 1, s.y);
  atomicAdd(sp + 2, s.z); atomicAdd(sp + 3, s.w);
  atomicAdd(qp + 0, ss.x); atomicAdd(qp + 1, ss.y);
  atomicAdd(qp + 2, ss.z); atomicAdd(qp + 3, ss.w);
}

__global__ void gn_finalize_kernel(const float* __restrict__ stats, const int* __restrict__ cntInt,
                                   const float* __restrict__ gnw, const float* __restrict__ gnb,
                                   const float* __restrict__ gnms, int row,
                                   float* __restrict__ scsh) {
  int i = blockIdx.x * 256 + threadIdx.x;
  if (i >= NGRAPH * HC) return;
  int g = i / HC, f = i - g * HC;
  float c = fmaxf((float)cntInt[g], 1.0f);
  float m = stats[i] / c;
  float sq = stats[NGRAPH * HC + i] / c;
  float ms = gnms[row * HC + f];
  float var = sq - m * m * ms * (2.0f - ms);
  float w = gnw[row * HC + f], b = gnb[row * HC + f];
  float scale = w / sqrtf(var + 1e-5f);
  float shift = b - scale * ms * m;
  scsh[i] = scale;
  scsh[NGRAPH * HC + i] = shift;
}

// =====================================================================
// Per-graph node counts via binary search over the SORTED batch array.
// =====================================================================
__global__ void cnt_bsearch_kernel(const int* __restrict__ batch, int* __restrict__ cntInt) {
  int g = threadIdx.x;
  if (g >= NGRAPH) return;
  auto lb = [&](int v) {
    int lo = 0, hi = N_NODES;
    while (lo < hi) {
      int mid = (lo + hi) >> 1;
      if (batch[mid] < v) lo = mid + 1; else hi = mid;
    }
    return lo;
  };
  int a = lb(g), b = lb(g + 1);
  cntInt[g] = b - a;
}

// =====================================================================
// CSR build by destination
// =====================================================================
__global__ void deg_hist_kernel(const int* __restrict__ dstE, int* __restrict__ deg) {
  int e = blockIdx.x * 256 + threadIdx.x;
  if (e < N_EDGES) atomicAdd(&deg[dstE[e]], 1);
}

__global__ void scan1_kernel(const int* __restrict__ deg, int* __restrict__ bsum) {
  __shared__ int sd[256];
  int i = blockIdx.x * 256 + threadIdx.x;
  sd[threadIdx.x] = (i < N_NODES) ? deg[i] : 0;
  __syncthreads();
  for (int s = 128; s > 0; s >>= 1) {
    if (threadIdx.x < s) sd[threadIdx.x] += sd[threadIdx.x + s];
    __syncthreads();
  }
  if (threadIdx.x == 0) bsum[blockIdx.x] = sd[0];
}

__global__ void scan2_kernel(int* __restrict__ bsum, int nb) {
  __shared__ int sd[256];
  int t = threadIdx.x;
  int v0 = (t < nb) ? bsum[t] : 0;
  sd[t] = v0;
  __syncthreads();
  for (int s = 1; s < 256; s <<= 1) {
    int v = (t >= s) ? sd[t - s] : 0;
    __syncthreads();
    sd[t] += v;
    __syncthreads();
  }
  if (t < nb) bsum[t] = sd[t] - v0;  // exclusive
}

__global__ void scan3_kernel(const int* __restrict__ deg, const int* __restrict__ bsum,
                             int* __restrict__ rowptr) {
  __shared__ int sd[256];
  int i = blockIdx.x * 256 + threadIdx.x;
  int t = threadIdx.x;
  int d = (i < N_NODES) ? deg[i] : 0;
  sd[t] = d;
  __syncthreads();
  for (int s = 1; s < 256; s <<= 1) {
    int v = (t >= s) ? sd[t - s] : 0;
    __syncthreads();
    sd[t] += v;
    __syncthreads();
  }
  if (i < N_NODES) rowptr[i] = bsum[blockIdx.x] + sd[t] - d;
  if (i == 0) rowptr[N_NODES] = N_EDGES;
}

__global__ void scatter_kernel(const int* __restrict__ srcE, const int* __restrict__ dstE,
                               const int* __restrict__ rowptr, int* __restrict__ fill,
                               int* __restrict__ colA) {
  int e = blockIdx.x * 256 + threadIdx.x;
  if (e < N_EDGES) {
    int d = dstE[e];
    int pos = rowptr[d] + atomicAdd(&fill[d], 1);
    colA[pos] = srcE[e];
  }
}

// =====================================================================
// GATv2 attention (R9 proven form: wg=256, 4 nodes/block, 2-wide loop,
// no LDS, no atomics). Tiny logits -> direct exp.
// Lane L (<44) owns features 4L..4L+3 (one head per lane group of 4).
// =====================================================================
#define AEDGE(V, D, ACC)                                                      \
  do {                                                                        \
    float e0 = (V).x + xrv.x; e0 = fmaxf(e0, 0.2f * e0);                      \
    float e1 = (V).y + xrv.y; e1 = fmaxf(e1, 0.2f * e1);                      \
    float e2 = (V).z + xrv.z; e2 = fmaxf(e2, 0.2f * e2);                      \
    float e3 = (V).w + xrv.w; e3 = fmaxf(e3, 0.2f * e3);                      \
    float p = fmaf(e3, av.w, fmaf(e2, av.z, fmaf(e1, av.y, e0 * av.x)));      \
    p += __shfl_xor(p, 1);                                                    \
    p += __shfl_xor(p, 2);                                                    \
    float pp = __expf(p);                                                     \
    (D) += pp;                                                                \
    (ACC).x = fmaf(pp, (V).x, (ACC).x);                                       \
    (ACC).y = fmaf(pp, (V).y, (ACC).y);                                       \
    (ACC).z = fmaf(pp, (V).z, (ACC).z);                                       \
    (ACC).w = fmaf(pp, (V).w, (ACC).w);                                       \
  } while (0)

__global__ __launch_bounds__(256) void attn_concat_kernel(
    const float* __restrict__ xl, const float* __restrict__ xr,
    const float* __restrict__ att, const int* __restrict__ rowptr,
    const int* __restrict__ colA, float* __restrict__ out) {
  int t = threadIdx.x;
  int node = blockIdx.x * 4 + (t >> 6);
  int lane = t & 63;
  if (lane >= 44 || node >= N_NODES) return;
  const float4 av = *(const float4*)(att + lane * 4);
  size_t base = (size_t)node * HC + lane * 4;
  const float4 xrv = *(const float4*)(xr + base);
  int start = rowptr[node], end = rowptr[node + 1];
  float d = 0.0f, dB = 0.0f;
  float4 acc = make_float4(0.f, 0.f, 0.f, 0.f);
  float4 accB = make_float4(0.f, 0.f, 0.f, 0.f);
  float4 p1, p2;
  if (start < end)     p1 = *(const float4*)(xl + (size_t)colA[start] * HC + lane * 4);
  if (start + 1 < end) p2 = *(const float4*)(xl + (size_t)colA[start + 1] * HC + lane * 4);
  {
    float4 sv = *(const float4*)(xl + base);  // self-loop
    AEDGE(sv, d, acc);
  }
  int j = start;
  for (; j + 3 < end; j += 2) {
    float4 n1 = *(const float4*)(xl + (size_t)colA[j + 2] * HC + lane * 4);
    float4 n2 = *(const float4*)(xl + (size_t)colA[j + 3] * HC + lane * 4);
    AEDGE(p1, d, acc);
    AEDGE(p2, dB, accB);
    p1 = n1; p2 = n2;
  }
  if (j < end)     AEDGE(p1, d, acc);
  if (j + 1 < end) AEDGE(p2, dB, accB);
  if (j + 2 < end) {
    float4 n1 = *(const float4*)(xl + (size_t)colA[j + 2] * HC + lane * 4);
    AEDGE(n1, d, acc);
  }
  d += dB;
  acc.x += accB.x; acc.y += accB.y; acc.z += accB.z; acc.w += accB.w;
  float rd = 1.0f / (d + 1e-16f);
  float4 o = *(const float4*)(out + base);  // residual+bias already there
  o.x = fmaf(acc.x, rd, o.x);
  o.y = fmaf(acc.y, rd, o.y);
  o.z = fmaf(acc.z, rd, o.z);
  o.w = fmaf(acc.w, rd, o.w);
  *(float4*)(out + base) = o;
}

__global__ __launch_bounds__(256) void attn_mean_kernel(
    const float* __restrict__ xl, const float* __restrict__ xr,
    const float* __restrict__ att, const int* __restrict__ rowptr,
    const int* __restrict__ colA, const float* __restrict__ res16,
    float* __restrict__ out16) {
  int t = threadIdx.x;
  int node = blockIdx.x * 4 + (t >> 6);
  int lane = t & 63;
  if (node >= N_NODES) return;
  int L = (lane < 44) ? lane : 0;  // lanes 44..63 ride along (zeroed later)
  const float4 av = *(const float4*)(att + L * 4);
  size_t base = (size_t)node * HC + L * 4;
  const float4 xrv = *(const float4*)(xr + base);
  int start = rowptr[node], end = rowptr[node + 1];
  float d = 0.0f, dB = 0.0f;
  float4 acc = make_float4(0.f, 0.f, 0.f, 0.f);
  float4 accB = make_float4(0.f, 0.f, 0.f, 0.f);
  float4 p1, p2;
  if (start < end)     p1 = *(const float4*)(xl + (size_t)colA[start] * HC + L * 4);
  if (start + 1 < end) p2 = *(const float4*)(xl + (size_t)colA[start + 1] * HC + L * 4);
  {
    float4 sv = *(const float4*)(xl + base);
    AEDGE(sv, d, acc);
  }
  int j = start;
  for (; j + 3 < end; j += 2) {
    float4 n1 = *(const float4*)(xl + (size_t)colA[j + 2] * HC + L * 4);
    float4 n2 = *(const float4*)(xl + (size_t)colA[j + 3] * HC + L * 4);
    AEDGE(p1, d, acc);
    AEDGE(p2, dB, accB);
    p1 = n1; p2 = n2;
  }
  if (j < end)     AEDGE(p1, d, acc);
  if (j + 1 < end) AEDGE(p2, dB, accB);
  if (j + 2 < end) {
    float4 n1 = *(const float4*)(xl + (size_t)colA[j + 2] * HC + L * 4);
    AEDGE(n1, d, acc);
  }
  d += dB;
  acc.x += accB.x; acc.y += accB.y; acc.z += accB.z; acc.w += accB.w;
  float rd = 1.0f / (d + 1e-16f);
  float4 o;
  o.x = (lane < 44) ? acc.x * rd : 0.0f;
  o.y = (lane < 44) ? acc.y * rd : 0.0f;
  o.z = (lane < 44) ? acc.z * rd : 0.0f;
  o.w = (lane < 44) ? acc.w * rd : 0.0f;
#pragma unroll
  for (int w = 4; w <= 32; w <<= 1) {
    o.x += __shfl_xor(o.x, w);
    o.y += __shfl_xor(o.y, w);
    o.z += __shfl_xor(o.z, w);
    o.w += __shfl_xor(o.w, w);
  }
  if (lane < 4) {
    const float* rp = res16 + (size_t)node * 16 + lane * 4;
    float4 r = *(const float4*)rp;
    float4 ov;
    ov.x = fmaxf(fmaf(o.x, 1.0f / 11.0f, r.x), 0.0f);
    ov.y = fmaxf(fmaf(o.y, 1.0f / 11.0f, r.y), 0.0f);
    ov.z = fmaxf(fmaf(o.z, 1.0f / 11.0f, r.z), 0.0f);
    ov.w = fmaxf(fmaf(o.w, 1.0f / 11.0f, r.w), 0.0f);
    *(float4*)(out16 + (size_t)node * 16 + lane * 4) = ov;
  }
}

// =====================================================================
// res16 = normApply(h) @ c5_Wres(176x16) + c5_b   (norm+relu fused in load)
// =====================================================================
__global__ __launch_bounds__(256) void res16_kernel(const float* __restrict__ h,
                                                    const float* __restrict__ scsh,
                                                    const int* __restrict__ batch,
                                                    const float* __restrict__ Wres,
                                                    const float* __restrict__ b16,
                                                    float* __restrict__ res16) {
  __shared__ float Ws[176 * 16];
  __shared__ float hs[16 * 176];
  int t = threadIdx.x;
  for (int i = t; i < 176 * 16; i += 256) Ws[i] = Wres[i];
  int n0 = blockIdx.x * 16;
  for (int i = t; i < 16 * 176; i += 256) {
    int row = i / 176, k = i - row * 176;
    int g = batch[n0 + row];
    float v = h[(size_t)n0 * HC + i];
    hs[i] = fmaxf(fmaf(v, scsh[g * HC + k], scsh[(NGRAPH + g) * HC + k]), 0.0f);
  }
  __syncthreads();
  int tx = t & 15, ty = t >> 4;
  float acc = b16[tx];
  for (int k = 0; k < HC; k++) acc = fmaf(hs[ty * HC + k], Ws[k * 16 + tx], acc);
  res16[(size_t)(n0 + ty) * 16 + tx] = acc;
}

// =====================================================================
// Head MLP
// =====================================================================
__global__ __launch_bounds__(256) void head_kernel(
    const float* __restrict__ in16, const float* __restrict__ Wo1,
    const float* __restrict__ bo1, const float* __restrict__ Wo2,
    const float* __restrict__ bo2, const float* __restrict__ Wc,
    const float* __restrict__ bc, float* __restrict__ outp) {
  __shared__ float w1[256], w2[512], wcS[320], b1[16], b2[32], bcS[10];
  int t = threadIdx.x;
  for (int i = t; i < 256; i += 256) w1[i] = Wo1[i];
  for (int i = t; i < 512; i += 256) w2[i] = Wo2[i];
  for (int i = t; i < 320; i += 256) wcS[i] = Wc[i];
  if (t < 16) b1[t] = bo1[t];
  if (t < 32) b2[t] = bo2[t];
  if (t < 10) bcS[t] = bc[t];
  __syncthreads();
  int n = blockIdx.x * 256 + t;
  if (n >= N_NODES) return;
  float x[16];
#pragma unroll
  for (int i = 0; i < 16; i++) x[i] = in16[(size_t)n * 16 + i];
  float o1[16];
#pragma unroll
  for (int j = 0; j < 16; j++) {
    float a = b1[j];
#pragma unroll
    for (int k = 0; k < 16; k++) a = fmaf(x[k], w1[k * 16 + j], a);
    o1[j] = fmaxf(a, 0.0f);
  }
  float o2[32];
#pragma unroll
  for (int j = 0; j < 32; j++) {
    float a = b2[j];
#pragma unroll
    for (int k = 0; k < 16; k++) a = fmaf(o1[k], w2[k * 32 + j], a);
    o2[j] = fmaxf(a, 0.0f);
  }
#pragma unroll
  for (int j = 0; j < 10; j++) {
    float a = bcS[j];
#pragma unroll
    for (int k = 0; k < 32; k++) a = fmaf(o2[k], wcS[k * 10 + j], a);
    outp[(size_t)n * 10 + j] = a;
  }
}

// =====================================================================
extern "C" void kernel_launch(void* const* d_in, const int* in_sizes, int n_in,
                              void* d_out, int out_size, void* d_ws, size_t ws_size,
                              hipStream_t stream) {
  (void)in_sizes; (void)n_in; (void)out_size; (void)ws_size;
  const float* x     = (const float*)d_in[0];
  const int*   ei    = (const int*)d_in[1];
  const int*   srcE  = ei;
  const int*   dstE  = ei + N_EDGES;
  const int*   batch = (const int*)d_in[2];
  const float* W_pre = (const float*)d_in[3];
  const float* b_pre = (const float*)d_in[4];
  const float* gn_w  = (const float*)d_in[5];
  const float* gn_b  = (const float*)d_in[6];
  const float* gn_ms = (const float*)d_in[7];
  const float* cWl   = (const float*)d_in[8];
  const float* cWr   = (const float*)d_in[9];
  const float* cAtt  = (const float*)d_in[10];
  const float* cB    = (const float*)d_in[11];
  const float* cWres = (const float*)d_in[12];
  const float* c5Wl  = (const float*)d_in[13];
  const float* c5Wr  = (const float*)d_in[14];
  const float* c5Att = (const float*)d_in[15];
  const float* c5b   = (const float*)d_in[16];
  const float* c5Wres= (const float*)d_in[17];
  const float* Wo1   = (const float*)d_in[18];
  const float* bo1   = (const float*)d_in[19];
  const float* Wo2   = (const float*)d_in[20];
  const float* bo2   = (const float*)d_in[21];
  const float* Wc    = (const float*)d_in[22];
  const float* bc    = (const float*)d_in[23];

  const size_t FB = (size_t)N_NODES * HC;
  const size_t STB = (size_t)2 * NGRAPH * HC;  // one stats buffer (22528 floats)
  float* ws    = (float*)d_ws;
  float* buf0  = ws;
  float* buf1  = ws + FB;
  float* buf2  = ws + 2 * FB;
  float* buf3  = ws + 3 * FB;
  float* res16 = ws + 4 * FB;
  float* out16 = res16 + (size_t)N_NODES * 16;
  float* stats = out16 + (size_t)N_NODES * 16;         // 5 buffers
  float* scsh  = stats + 5 * STB;
  _Float16* wph = (_Float16*)(scsh + STB);             // 991232 halves
  int* ibase   = (int*)((char*)wph + (size_t)991232 * 2);
  int* cntInt  = ibase;
  int* deg     = ibase + 64;
  int* fill    = deg + N_NODES;
  int* rowptr  = fill + N_NODES;
  int* colA    = rowptr + N_NODES + 1;
  int* bsum    = colA + N_EDGES;

  const int NB = (N_NODES + 255) / 256;

  hipMemsetAsync(deg, 0, sizeof(int) * 2 * N_NODES, stream);
  hipMemsetAsync(stats, 0, sizeof(float) * 5 * STB, stream);  // all layers at once

  prep_kernel<<<(TOT_PAIRS + 255) / 256, 256, 0, stream>>>(W_pre, cWl, cWr, cWres, c5Wl, c5Wr, wph);
  cnt_bsearch_kernel<<<1, 64, 0, stream>>>(batch, cntInt);
  deg_hist_kernel<<<(N_EDGES + 255) / 256, 256, 0, stream>>>(dstE, deg);
  scan1_kernel<<<NB, 256, 0, stream>>>(deg, bsum);
  scan2_kernel<<<1, 256, 0, stream>>>(bsum, NB);
  scan3_kernel<<<NB, 256, 0, stream>>>(deg, bsum, rowptr);
  scatter_kernel<<<(N_EDGES + 255) / 256, 256, 0, stream>>>(srcE, dstE, rowptr, fill, colA);

  // pre: buf0 = x @ W_pre + b_pre  (raw, no norm on input)
  gemm_mfma<<<GX8 * 1 * 8, 256, 0, stream>>>(x, N_NODES, IN_F, 4, 1, wph, 0,
                                             nullptr, nullptr,
                                             b_pre, nullptr, nullptr,
                                             buf0, nullptr, nullptr);
  gn_stats_kernel<<<(N_NODES + 255) / 256, 256, 0, stream>>>(buf0, batch, stats);
  gn_finalize_kernel<<<(NGRAPH * HC + 255) / 256, 256, 0, stream>>>(stats, cntInt, gn_w, gn_b, gn_ms, 0, scsh);

  float* h = buf0;  // raw buffer; norm applied on the fly by consumers
  float* o = buf3;
  for (int i = 0; i < 4; i++) {
    const _Float16* Wcat_i = wph + PREH + (size_t)(3 * i) * MATH;
    gemm_mfma<<<GX8 * 3 * 8, 256, 0, stream>>>(h, N_NODES, HC, 6, 3, Wcat_i, MATH,
                                               scsh, batch,
                                               nullptr, nullptr, cB + i * HC,
                                               buf1, buf2, o);
    attn_concat_kernel<<<(N_NODES + 3) / 4, 256, 0, stream>>>(buf1, buf2, cAtt + i * HC, rowptr, colA, o);
    float* st = stats + (size_t)(i + 1) * STB;
    gn_stats_kernel<<<(N_NODES + 255) / 256, 256, 0, stream>>>(o, batch, st);
    gn_finalize_kernel<<<(NGRAPH * HC + 255) / 256, 256, 0, stream>>>(st, cntInt, gn_w, gn_b, gn_ms, i + 1, scsh);
    float* tmp = h; h = o; o = tmp;
  }

  // conv5 (input = raw h with scsh row 4 fused in consumers)
  const _Float16* Wc5 = wph + PREH + (size_t)12 * MATH;
  gemm_mfma<<<GX8 * 2 * 8, 256, 0, stream>>>(h, N_NODES, HC, 6, 2, Wc5, MATH,
                                             scsh, batch,
                                             nullptr, nullptr, nullptr,
                                             buf1, buf2, nullptr);
  res16_kernel<<<N_NODES / 16, 256, 0, stream>>>(h, scsh, batch, c5Wres, c5b, res16);
  attn_mean_kernel<<<(N_NODES + 3) / 4, 256, 0, stream>>>(buf1, buf2, c5Att, rowptr, colA, res16, out16);

  head_kernel<<<NB, 256, 0, stream>>>(out16, Wo1, bo1, Wo2, bo2, Wc, bc, (float*)d_out);
}

// Round 13
// 857.325 us; speedup vs baseline: 1.0011x; 1.0011x over previous
//
#include <hip/hip_runtime.h>
#include <math.h>

#define N_NODES 50000
#define N_EDGES 400000
#define IN_F 128
#define HC 176
#define NGRAPH 64

typedef _Float16 half8 __attribute__((ext_vector_type(8)));
typedef float floatx4 __attribute__((ext_vector_type(4)));

// =====================================================================
// Packed split-fp16 weights in MFMA B-fragment order.
// For each matrix: [kc][ct][s(hi/lo)][lane][j]  (halves)
//   value = W[kc*32 + (lane>>4)*8 + j][ct*16 + (lane&15)]  (0 if k >= K)
// Mat order: pre(nkc=4) | 4 layers x {Wl,Wr,Wres}(nkc=6) | c5Wl,c5Wr(nkc=6)
// =====================================================================
#define PREH 45056   // 4*11*2*512 halves
#define MATH 67584   // 6*11*2*512 halves
#define TOT_PAIRS 495616  // 22528 + 14*33792
#define KCBYTES 22528     // bytes per kc chunk (11*2*512*2)
#define GX8 49            // row-tile groups of 8 (49*8=392 >= 391 tiles)

__global__ void prep_kernel(const float* __restrict__ Wpre,
                            const float* __restrict__ cWl, const float* __restrict__ cWr,
                            const float* __restrict__ cWres,
                            const float* __restrict__ c5Wl, const float* __restrict__ c5Wr,
                            _Float16* __restrict__ wp) {
  int gid = blockIdx.x * 256 + threadIdx.x;
  if (gid >= TOT_PAIRS) return;
  int mat, idx;
  if (gid < 22528) { mat = 0; idx = gid; }
  else { int g = gid - 22528; mat = 1 + g / 33792; idx = g % 33792; }
  int kc = idx / 5632;
  int rem = idx - kc * 5632;
  int ct = rem / 512;
  int li = rem - ct * 512;
  int lane = li >> 3, j = li & 7;
  int k = kc * 32 + ((lane >> 4) << 3) + j;
  int col = ct * 16 + (lane & 15);
  const float* src; int Ksrc; size_t base;
  if (mat == 0) { src = Wpre; Ksrc = 128; base = 0; }
  else if (mat <= 12) {
    int lm = mat - 1; int layer = lm / 3; int sub = lm - layer * 3;
    const float* s = (sub == 0) ? cWl : (sub == 1) ? cWr : cWres;
    src = s + (size_t)layer * HC * HC; Ksrc = HC;
    base = PREH + (size_t)lm * MATH;
  } else {
    src = (mat == 13) ? c5Wl : c5Wr; Ksrc = HC;
    base = PREH + (size_t)12 * MATH + (size_t)(mat - 13) * MATH;
  }
  float v = (k < Ksrc) ? src[(size_t)k * HC + col] : 0.0f;
  _Float16 h = (_Float16)v;
  _Float16 l = (_Float16)(v - (float)h);
  size_t o = base + (size_t)(kc * 11 + ct) * 1024 + li;
  wp[o] = h;
  wp[o + 512] = l;
}

// =====================================================================
// Split-fp16 MFMA GEMM with block-level LDS staging of B (R7 structure)
// + XCD-aware block swizzle (R8): blocks sharing the same A row-tile but
// different mat have blockIdx.x differing by 8 -> same XCD.
// grid.x = GX8 * nmat * 8.
// =====================================================================
__global__ __launch_bounds__(256, 2) void gemm_mfma(
    const float* __restrict__ A, int M, int K, int nkc, int nmat,
    const _Float16* __restrict__ Wp, int matStride,
    const float* __restrict__ scsh, const int* __restrict__ batch,
    const float* __restrict__ bias0, const float* __restrict__ bias1,
    const float* __restrict__ bias2,
    float* __restrict__ out0, float* __restrict__ out1, float* __restrict__ out2) {
  __shared__ __align__(16) char smem[2 * KCBYTES];
  const int b = blockIdx.x;
  const int grp = b >> 3, sub = b & 7;
  const int mat = grp % nmat;
  const int tile = ((grp / nmat) << 3) | sub;
  if (tile * 128 >= M) return;
  const _Float16* W = Wp + (size_t)mat * matStride;
  float* outp = (mat == 0) ? out0 : (mat == 1) ? out1 : out2;
  const float* bias = (mat == 0) ? bias0 : (mat == 1) ? bias1 : bias2;
  const int tid = threadIdx.x;
  const int lane = tid & 63;
  const int wv = tid >> 6;
  const int m16 = lane & 15, quad = lane >> 4;
  const int kb = quad << 3;
  const int rowBase = tile * 128 + wv * 32;
  const int rA0 = min(rowBase + m16, M - 1);
  const int rA1 = min(rowBase + 16 + m16, M - 1);
  const float* ap0 = A + (size_t)rA0 * K + kb;
  const float* ap1 = A + (size_t)rA1 * K + kb;
  const float* sc0 = nullptr; const float* sh0 = nullptr;
  const float* sc1 = nullptr; const float* sh1 = nullptr;
  if (scsh) {
    int g0 = batch[rA0], g1 = batch[rA1];
    sc0 = scsh + (size_t)g0 * HC + kb;
    sh0 = scsh + (size_t)(NGRAPH + g0) * HC + kb;
    sc1 = scsh + (size_t)g1 * HC + kb;
    sh1 = scsh + (size_t)(NGRAPH + g1) * HC + kb;
  }

  auto stage = [&](int kc, int buf) {
    const char* src = (const char*)W + (size_t)kc * KCBYTES;
    char* dst = smem + buf * KCBYTES;
#pragma unroll
    for (int i = 0; i < 6; i++) {
      int idx = wv * 6 + i;
      if (idx < 22) {
        __builtin_amdgcn_global_load_lds(
            (const __attribute__((address_space(1))) unsigned int*)(src + idx * 1024 + lane * 16),
            (__attribute__((address_space(3))) unsigned int*)(dst + idx * 1024),
            16, 0, 0);
      }
    }
  };

  floatx4 acc0[11], acc1[11];
#pragma unroll
  for (int ct = 0; ct < 11; ct++)
#pragma unroll
    for (int r = 0; r < 4; r++) { acc0[ct][r] = 0.0f; acc1[ct][r] = 0.0f; }

  stage(0, 0);

  for (int kc = 0; kc < nkc; kc++) {
    const int buf = kc & 1;
    __syncthreads();
    if (kc + 1 < nkc) stage(kc + 1, 1 - buf);

    const int koff = kc << 5;
    float va0[8], va1[8];
    if (koff + kb + 8 <= K) {
      float4 u0 = *(const float4*)(ap0 + koff);
      float4 u1 = *(const float4*)(ap0 + koff + 4);
      float4 w0 = *(const float4*)(ap1 + koff);
      float4 w1 = *(const float4*)(ap1 + koff + 4);
      va0[0] = u0.x; va0[1] = u0.y; va0[2] = u0.z; va0[3] = u0.w;
      va0[4] = u1.x; va0[5] = u1.y; va0[6] = u1.z; va0[7] = u1.w;
      va1[0] = w0.x; va1[1] = w0.y; va1[2] = w0.z; va1[3] = w0.w;
      va1[4] = w1.x; va1[5] = w1.y; va1[6] = w1.z; va1[7] = w1.w;
      if (scsh) {
        float s0[8], h0[8], s1[8], h1[8];
        float4 t;
        t = *(const float4*)(sc0 + koff);     s0[0]=t.x; s0[1]=t.y; s0[2]=t.z; s0[3]=t.w;
        t = *(const float4*)(sc0 + koff + 4); s0[4]=t.x; s0[5]=t.y; s0[6]=t.z; s0[7]=t.w;
        t = *(const float4*)(sh0 + koff);     h0[0]=t.x; h0[1]=t.y; h0[2]=t.z; h0[3]=t.w;
        t = *(const float4*)(sh0 + koff + 4); h0[4]=t.x; h0[5]=t.y; h0[6]=t.z; h0[7]=t.w;
        t = *(const float4*)(sc1 + koff);     s1[0]=t.x; s1[1]=t.y; s1[2]=t.z; s1[3]=t.w;
        t = *(const float4*)(sc1 + koff + 4); s1[4]=t.x; s1[5]=t.y; s1[6]=t.z; s1[7]=t.w;
        t = *(const float4*)(sh1 + koff);     h1[0]=t.x; h1[1]=t.y; h1[2]=t.z; h1[3]=t.w;
        t = *(const float4*)(sh1 + koff + 4); h1[4]=t.x; h1[5]=t.y; h1[6]=t.z; h1[7]=t.w;
#pragma unroll
        for (int j = 0; j < 8; j++) {
          va0[j] = fmaxf(fmaf(va0[j], s0[j], h0[j]), 0.0f);
          va1[j] = fmaxf(fmaf(va1[j], s1[j], h1[j]), 0.0f);
        }
      }
    } else {
#pragma unroll
      for (int j = 0; j < 8; j++) { va0[j] = 0.0f; va1[j] = 0.0f; }
    }
    half8 ah0, al0, ah1, al1;
#pragma unroll
    for (int j = 0; j < 8; j++) {
      _Float16 h = (_Float16)va0[j];
      ah0[j] = h; al0[j] = (_Float16)(va0[j] - (float)h);
      _Float16 g = (_Float16)va1[j];
      ah1[j] = g; al1[j] = (_Float16)(va1[j] - (float)g);
    }
    const char* bbase = smem + buf * KCBYTES + lane * 16;
#pragma unroll
    for (int ct = 0; ct < 11; ct++) {
      half8 bh = *(const half8*)(bbase + ct * 2048);
      half8 bl = *(const half8*)(bbase + ct * 2048 + 1024);
      acc0[ct] = __builtin_amdgcn_mfma_f32_16x16x32_f16(ah0, bh, acc0[ct], 0, 0, 0);
      acc1[ct] = __builtin_amdgcn_mfma_f32_16x16x32_f16(ah1, bh, acc1[ct], 0, 0, 0);
      acc0[ct] = __builtin_amdgcn_mfma_f32_16x16x32_f16(al0, bh, acc0[ct], 0, 0, 0);
      acc1[ct] = __builtin_amdgcn_mfma_f32_16x16x32_f16(al1, bh, acc1[ct], 0, 0, 0);
      acc0[ct] = __builtin_amdgcn_mfma_f32_16x16x32_f16(ah0, bl, acc0[ct], 0, 0, 0);
      acc1[ct] = __builtin_amdgcn_mfma_f32_16x16x32_f16(ah1, bl, acc1[ct], 0, 0, 0);
    }
  }

  float bv[11];
#pragma unroll
  for (int ct = 0; ct < 11; ct++) bv[ct] = bias ? bias[ct * 16 + m16] : 0.0f;
#pragma unroll
  for (int r = 0; r < 4; r++) {
    int row0 = rowBase + (quad << 2) + r;
    if (row0 < M) {
      float* op = outp + (size_t)row0 * HC + m16;
#pragma unroll
      for (int ct = 0; ct < 11; ct++) op[ct * 16] = acc0[ct][r] + bv[ct];
    }
    int row1 = row0 + 16;
    if (row1 < M) {
      float* op = outp + (size_t)row1 * HC + m16;
#pragma unroll
      for (int ct = 0; ct < 11; ct++) op[ct * 16] = acc1[ct][r] + bv[ct];
    }
  }
}

// =====================================================================
// GraphNorm stats, vectorized + parallel: grid = N/64 blocks (782),
// block covers 64 nodes, each WAVE walks only 16 nodes (short serial
// loop); lane L<44 accumulates features 4L..4L+3 via float4. Flush on
// graph change (batch sorted): ~1.1M atomics total (~6 us fabric cost
// per R11 calibration of 4.4M ~= 25 us). R12's 196-block version was
// under-parallel (<1 block/CU, 64-deep serial loop -> 37 us).
// =====================================================================
__global__ __launch_bounds__(256) void gn_stats_kernel(const float* __restrict__ h,
                                                       const int* __restrict__ batch,
                                                       float* __restrict__ stats) {
  int t = threadIdx.x;
  int wv = t >> 6, lane = t & 63;
  if (lane >= 44) return;
  int n0 = blockIdx.x * 64 + wv * 16;
  if (n0 >= N_NODES) return;
  int n1 = min(n0 + 16, N_NODES);
  int f4 = lane * 4;
  float4 s = make_float4(0.f, 0.f, 0.f, 0.f);
  float4 ss = make_float4(0.f, 0.f, 0.f, 0.f);
  int gcur = batch[n0];
  for (int n = n0; n < n1; n++) {
    int g = batch[n];
    if (g != gcur) {
      float* sp = stats + (size_t)gcur * HC + f4;
      float* qp = stats + (size_t)(NGRAPH + gcur) * HC + f4;
      atomicAdd(sp + 0, s.x); atomicAdd(sp + 1, s.y);
      atomicAdd(sp + 2, s.z); atomicAdd(sp + 3, s.w);
      atomicAdd(qp + 0, ss.x); atomicAdd(qp + 1, ss.y);
      atomicAdd(qp + 2, ss.z); atomicAdd(qp + 3, ss.w);
      s = make_float4(0.f, 0.f, 0.f, 0.f);
      ss = make_float4(0.f, 0.f, 0.f, 0.f);
      gcur = g;
    }
    float4 v = *(const float4*)(h + (size_t)n * HC + f4);
    s.x += v.x; s.y += v.y; s.z += v.z; s.w += v.w;
    ss.x = fmaf(v.x, v.x, ss.x); ss.y = fmaf(v.y, v.y, ss.y);
    ss.z = fmaf(v.z, v.z, ss.z); ss.w = fmaf(v.w, v.w, ss.w);
  }
  float* sp = stats + (size_t)gcur * HC + f4;
  float* qp = stats + (size_t)(NGRAPH + gcur) * HC + f4;
  atomicAdd(sp + 0, s.x); atomicAdd(sp + 1, s.y);
  atomicAdd(sp + 2, s.z); atomicAdd(sp + 3, s.w);
  atomicAdd(qp + 0, ss.x); atomicAdd(qp + 1, ss.y);
  atomicAdd(qp + 2, ss.z); atomicAdd(qp + 3, ss.w);
}

__global__ void gn_finalize_kernel(const float* __restrict__ stats, const int* __restrict__ cntInt,
                                   const float* __restrict__ gnw, const float* __restrict__ gnb,
                                   const float* __restrict__ gnms, int row,
                                   float* __restrict__ scsh) {
  int i = blockIdx.x * 256 + threadIdx.x;
  if (i >= NGRAPH * HC) return;
  int g = i / HC, f = i - g * HC;
  float c = fmaxf((float)cntInt[g], 1.0f);
  float m = stats[i] / c;
  float sq = stats[NGRAPH * HC + i] / c;
  float ms = gnms[row * HC + f];
  float var = sq - m * m * ms * (2.0f - ms);
  float w = gnw[row * HC + f], b = gnb[row * HC + f];
  float scale = w / sqrtf(var + 1e-5f);
  float shift = b - scale * ms * m;
  scsh[i] = scale;
  scsh[NGRAPH * HC + i] = shift;
}

// =====================================================================
// Per-graph node counts via binary search over the SORTED batch array.
// =====================================================================
__global__ void cnt_bsearch_kernel(const int* __restrict__ batch, int* __restrict__ cntInt) {
  int g = threadIdx.x;
  if (g >= NGRAPH) return;
  auto lb = [&](int v) {
    int lo = 0, hi = N_NODES;
    while (lo < hi) {
      int mid = (lo + hi) >> 1;
      if (batch[mid] < v) lo = mid + 1; else hi = mid;
    }
    return lo;
  };
  int a = lb(g), b = lb(g + 1);
  cntInt[g] = b - a;
}

// =====================================================================
// CSR build by destination
// =====================================================================
__global__ void deg_hist_kernel(const int* __restrict__ dstE, int* __restrict__ deg) {
  int e = blockIdx.x * 256 + threadIdx.x;
  if (e < N_EDGES) atomicAdd(&deg[dstE[e]], 1);
}

__global__ void scan1_kernel(const int* __restrict__ deg, int* __restrict__ bsum) {
  __shared__ int sd[256];
  int i = blockIdx.x * 256 + threadIdx.x;
  sd[threadIdx.x] = (i < N_NODES) ? deg[i] : 0;
  __syncthreads();
  for (int s = 128; s > 0; s >>= 1) {
    if (threadIdx.x < s) sd[threadIdx.x] += sd[threadIdx.x + s];
    __syncthreads();
  }
  if (threadIdx.x == 0) bsum[blockIdx.x] = sd[0];
}

__global__ void scan2_kernel(int* __restrict__ bsum, int nb) {
  __shared__ int sd[256];
  int t = threadIdx.x;
  int v0 = (t < nb) ? bsum[t] : 0;
  sd[t] = v0;
  __syncthreads();
  for (int s = 1; s < 256; s <<= 1) {
    int v = (t >= s) ? sd[t - s] : 0;
    __syncthreads();
    sd[t] += v;
    __syncthreads();
  }
  if (t < nb) bsum[t] = sd[t] - v0;  // exclusive
}

__global__ void scan3_kernel(const int* __restrict__ deg, const int* __restrict__ bsum,
                             int* __restrict__ rowptr) {
  __shared__ int sd[256];
  int i = blockIdx.x * 256 + threadIdx.x;
  int t = threadIdx.x;
  int d = (i < N_NODES) ? deg[i] : 0;
  sd[t] = d;
  __syncthreads();
  for (int s = 1; s < 256; s <<= 1) {
    int v = (t >= s) ? sd[t - s] : 0;
    __syncthreads();
    sd[t] += v;
    __syncthreads();
  }
  if (i < N_NODES) rowptr[i] = bsum[blockIdx.x] + sd[t] - d;
  if (i == 0) rowptr[N_NODES] = N_EDGES;
}

__global__ void scatter_kernel(const int* __restrict__ srcE, const int* __restrict__ dstE,
                               const int* __restrict__ rowptr, int* __restrict__ fill,
                               int* __restrict__ colA) {
  int e = blockIdx.x * 256 + threadIdx.x;
  if (e < N_EDGES) {
    int d = dstE[e];
    int pos = rowptr[d] + atomicAdd(&fill[d], 1);
    colA[pos] = srcE[e];
  }
}

// =====================================================================
// GATv2 attention (R9 proven form: wg=256, 4 nodes/block, 2-wide loop,
// no LDS, no atomics). Tiny logits -> direct exp.
// Lane L (<44) owns features 4L..4L+3 (one head per lane group of 4).
// =====================================================================
#define AEDGE(V, D, ACC)                                                      \
  do {                                                                        \
    float e0 = (V).x + xrv.x; e0 = fmaxf(e0, 0.2f * e0);                      \
    float e1 = (V).y + xrv.y; e1 = fmaxf(e1, 0.2f * e1);                      \
    float e2 = (V).z + xrv.z; e2 = fmaxf(e2, 0.2f * e2);                      \
    float e3 = (V).w + xrv.w; e3 = fmaxf(e3, 0.2f * e3);                      \
    float p = fmaf(e3, av.w, fmaf(e2, av.z, fmaf(e1, av.y, e0 * av.x)));      \
    p += __shfl_xor(p, 1);                                                    \
    p += __shfl_xor(p, 2);                                                    \
    float pp = __expf(p);                                                     \
    (D) += pp;                                                                \
    (ACC).x = fmaf(pp, (V).x, (ACC).x);                                       \
    (ACC).y = fmaf(pp, (V).y, (ACC).y);                                       \
    (ACC).z = fmaf(pp, (V).z, (ACC).z);                                       \
    (ACC).w = fmaf(pp, (V).w, (ACC).w);                                       \
  } while (0)

__global__ __launch_bounds__(256) void attn_concat_kernel(
    const float* __restrict__ xl, const float* __restrict__ xr,
    const float* __restrict__ att, const int* __restrict__ rowptr,
    const int* __restrict__ colA, float* __restrict__ out) {
  int t = threadIdx.x;
  int node = blockIdx.x * 4 + (t >> 6);
  int lane = t & 63;
  if (lane >= 44 || node >= N_NODES) return;
  const float4 av = *(const float4*)(att + lane * 4);
  size_t base = (size_t)node * HC + lane * 4;
  const float4 xrv = *(const float4*)(xr + base);
  int start = rowptr[node], end = rowptr[node + 1];
  float d = 0.0f, dB = 0.0f;
  float4 acc = make_float4(0.f, 0.f, 0.f, 0.f);
  float4 accB = make_float4(0.f, 0.f, 0.f, 0.f);
  float4 p1, p2;
  if (start < end)     p1 = *(const float4*)(xl + (size_t)colA[start] * HC + lane * 4);
  if (start + 1 < end) p2 = *(const float4*)(xl + (size_t)colA[start + 1] * HC + lane * 4);
  {
    float4 sv = *(const float4*)(xl + base);  // self-loop
    AEDGE(sv, d, acc);
  }
  int j = start;
  for (; j + 3 < end; j += 2) {
    float4 n1 = *(const float4*)(xl + (size_t)colA[j + 2] * HC + lane * 4);
    float4 n2 = *(const float4*)(xl + (size_t)colA[j + 3] * HC + lane * 4);
    AEDGE(p1, d, acc);
    AEDGE(p2, dB, accB);
    p1 = n1; p2 = n2;
  }
  if (j < end)     AEDGE(p1, d, acc);
  if (j + 1 < end) AEDGE(p2, dB, accB);
  if (j + 2 < end) {
    float4 n1 = *(const float4*)(xl + (size_t)colA[j + 2] * HC + lane * 4);
    AEDGE(n1, d, acc);
  }
  d += dB;
  acc.x += accB.x; acc.y += accB.y; acc.z += accB.z; acc.w += accB.w;
  float rd = 1.0f / (d + 1e-16f);
  float4 o = *(const float4*)(out + base);  // residual+bias already there
  o.x = fmaf(acc.x, rd, o.x);
  o.y = fmaf(acc.y, rd, o.y);
  o.z = fmaf(acc.z, rd, o.z);
  o.w = fmaf(acc.w, rd, o.w);
  *(float4*)(out + base) = o;
}

__global__ __launch_bounds__(256) void attn_mean_kernel(
    const float* __restrict__ xl, const float* __restrict__ xr,
    const float* __restrict__ att, const int* __restrict__ rowptr,
    const int* __restrict__ colA, const float* __restrict__ res16,
    float* __restrict__ out16) {
  int t = threadIdx.x;
  int node = blockIdx.x * 4 + (t >> 6);
  int lane = t & 63;
  if (node >= N_NODES) return;
  int L = (lane < 44) ? lane : 0;  // lanes 44..63 ride along (zeroed later)
  const float4 av = *(const float4*)(att + L * 4);
  size_t base = (size_t)node * HC + L * 4;
  const float4 xrv = *(const float4*)(xr + base);
  int start = rowptr[node], end = rowptr[node + 1];
  float d = 0.0f, dB = 0.0f;
  float4 acc = make_float4(0.f, 0.f, 0.f, 0.f);
  float4 accB = make_float4(0.f, 0.f, 0.f, 0.f);
  float4 p1, p2;
  if (start < end)     p1 = *(const float4*)(xl + (size_t)colA[start] * HC + L * 4);
  if (start + 1 < end) p2 = *(const float4*)(xl + (size_t)colA[start + 1] * HC + L * 4);
  {
    float4 sv = *(const float4*)(xl + base);
    AEDGE(sv, d, acc);
  }
  int j = start;
  for (; j + 3 < end; j += 2) {
    float4 n1 = *(const float4*)(xl + (size_t)colA[j + 2] * HC + L * 4);
    float4 n2 = *(const float4*)(xl + (size_t)colA[j + 3] * HC + L * 4);
    AEDGE(p1, d, acc);
    AEDGE(p2, dB, accB);
    p1 = n1; p2 = n2;
  }
  if (j < end)     AEDGE(p1, d, acc);
  if (j + 1 < end) AEDGE(p2, dB, accB);
  if (j + 2 < end) {
    float4 n1 = *(const float4*)(xl + (size_t)colA[j + 2] * HC + L * 4);
    AEDGE(n1, d, acc);
  }
  d += dB;
  acc.x += accB.x; acc.y += accB.y; acc.z += accB.z; acc.w += accB.w;
  float rd = 1.0f / (d + 1e-16f);
  float4 o;
  o.x = (lane < 44) ? acc.x * rd : 0.0f;
  o.y = (lane < 44) ? acc.y * rd : 0.0f;
  o.z = (lane < 44) ? acc.z * rd : 0.0f;
  o.w = (lane < 44) ? acc.w * rd : 0.0f;
#pragma unroll
  for (int w = 4; w <= 32; w <<= 1) {
    o.x += __shfl_xor(o.x, w);
    o.y += __shfl_xor(o.y, w);
    o.z += __shfl_xor(o.z, w);
    o.w += __shfl_xor(o.w, w);
  }
  if (lane < 4) {
    const float* rp = res16 + (size_t)node * 16 + lane * 4;
    float4 r = *(const float4*)rp;
    float4 ov;
    ov.x = fmaxf(fmaf(o.x, 1.0f / 11.0f, r.x), 0.0f);
    ov.y = fmaxf(fmaf(o.y, 1.0f / 11.0f, r.y), 0.0f);
    ov.z = fmaxf(fmaf(o.z, 1.0f / 11.0f, r.z), 0.0f);
    ov.w = fmaxf(fmaf(o.w, 1.0f / 11.0f, r.w), 0.0f);
    *(float4*)(out16 + (size_t)node * 16 + lane * 4) = ov;
  }
}

// =====================================================================
// res16 = normApply(h) @ c5_Wres(176x16) + c5_b   (norm+relu fused in load)
// =====================================================================
__global__ __launch_bounds__(256) void res16_kernel(const float* __restrict__ h,
                                                    const float* __restrict__ scsh,
                                                    const int* __restrict__ batch,
                                                    const float* __restrict__ Wres,
                                                    const float* __restrict__ b16,
                                                    float* __restrict__ res16) {
  __shared__ float Ws[176 * 16];
  __shared__ float hs[16 * 176];
  int t = threadIdx.x;
  for (int i = t; i < 176 * 16; i += 256) Ws[i] = Wres[i];
  int n0 = blockIdx.x * 16;
  for (int i = t; i < 16 * 176; i += 256) {
    int row = i / 176, k = i - row * 176;
    int g = batch[n0 + row];
    float v = h[(size_t)n0 * HC + i];
    hs[i] = fmaxf(fmaf(v, scsh[g * HC + k], scsh[(NGRAPH + g) * HC + k]), 0.0f);
  }
  __syncthreads();
  int tx = t & 15, ty = t >> 4;
  float acc = b16[tx];
  for (int k = 0; k < HC; k++) acc = fmaf(hs[ty * HC + k], Ws[k * 16 + tx], acc);
  res16[(size_t)(n0 + ty) * 16 + tx] = acc;
}

// =====================================================================
// Head MLP
// =====================================================================
__global__ __launch_bounds__(256) void head_kernel(
    const float* __restrict__ in16, const float* __restrict__ Wo1,
    const float* __restrict__ bo1, const float* __restrict__ Wo2,
    const float* __restrict__ bo2, const float* __restrict__ Wc,
    const float* __restrict__ bc, float* __restrict__ outp) {
  __shared__ float w1[256], w2[512], wcS[320], b1[16], b2[32], bcS[10];
  int t = threadIdx.x;
  for (int i = t; i < 256; i += 256) w1[i] = Wo1[i];
  for (int i = t; i < 512; i += 256) w2[i] = Wo2[i];
  for (int i = t; i < 320; i += 256) wcS[i] = Wc[i];
  if (t < 16) b1[t] = bo1[t];
  if (t < 32) b2[t] = bo2[t];
  if (t < 10) bcS[t] = bc[t];
  __syncthreads();
  int n = blockIdx.x * 256 + t;
  if (n >= N_NODES) return;
  float x[16];
#pragma unroll
  for (int i = 0; i < 16; i++) x[i] = in16[(size_t)n * 16 + i];
  float o1[16];
#pragma unroll
  for (int j = 0; j < 16; j++) {
    float a = b1[j];
#pragma unroll
    for (int k = 0; k < 16; k++) a = fmaf(x[k], w1[k * 16 + j], a);
    o1[j] = fmaxf(a, 0.0f);
  }
  float o2[32];
#pragma unroll
  for (int j = 0; j < 32; j++) {
    float a = b2[j];
#pragma unroll
    for (int k = 0; k < 16; k++) a = fmaf(o1[k], w2[k * 32 + j], a);
    o2[j] = fmaxf(a, 0.0f);
  }
#pragma unroll
  for (int j = 0; j < 10; j++) {
    float a = bcS[j];
#pragma unroll
    for (int k = 0; k < 32; k++) a = fmaf(o2[k], wcS[k * 10 + j], a);
    outp[(size_t)n * 10 + j] = a;
  }
}

// =====================================================================
extern "C" void kernel_launch(void* const* d_in, const int* in_sizes, int n_in,
                              void* d_out, int out_size, void* d_ws, size_t ws_size,
                              hipStream_t stream) {
  (void)in_sizes; (void)n_in; (void)out_size; (void)ws_size;
  const float* x     = (const float*)d_in[0];
  const int*   ei    = (const int*)d_in[1];
  const int*   srcE  = ei;
  const int*   dstE  = ei + N_EDGES;
  const int*   batch = (const int*)d_in[2];
  const float* W_pre = (const float*)d_in[3];
  const float* b_pre = (const float*)d_in[4];
  const float* gn_w  = (const float*)d_in[5];
  const float* gn_b  = (const float*)d_in[6];
  const float* gn_ms = (const float*)d_in[7];
  const float* cWl   = (const float*)d_in[8];
  const float* cWr   = (const float*)d_in[9];
  const float* cAtt  = (const float*)d_in[10];
  const float* cB    = (const float*)d_in[11];
  const float* cWres = (const float*)d_in[12];
  const float* c5Wl  = (const float*)d_in[13];
  const float* c5Wr  = (const float*)d_in[14];
  const float* c5Att = (const float*)d_in[15];
  const float* c5b   = (const float*)d_in[16];
  const float* c5Wres= (const float*)d_in[17];
  const float* Wo1   = (const float*)d_in[18];
  const float* bo1   = (const float*)d_in[19];
  const float* Wo2   = (const float*)d_in[20];
  const float* bo2   = (const float*)d_in[21];
  const float* Wc    = (const float*)d_in[22];
  const float* bc    = (const float*)d_in[23];

  const size_t FB = (size_t)N_NODES * HC;
  const size_t STB = (size_t)2 * NGRAPH * HC;  // one stats buffer (22528 floats)
  float* ws    = (float*)d_ws;
  float* buf0  = ws;
  float* buf1  = ws + FB;
  float* buf2  = ws + 2 * FB;
  float* buf3  = ws + 3 * FB;
  float* res16 = ws + 4 * FB;
  float* out16 = res16 + (size_t)N_NODES * 16;
  float* stats = out16 + (size_t)N_NODES * 16;         // 5 buffers
  float* scsh  = stats + 5 * STB;
  _Float16* wph = (_Float16*)(scsh + STB);             // 991232 halves
  int* ibase   = (int*)((char*)wph + (size_t)991232 * 2);
  int* cntInt  = ibase;
  int* deg     = ibase + 64;
  int* fill    = deg + N_NODES;
  int* rowptr  = fill + N_NODES;
  int* colA    = rowptr + N_NODES + 1;
  int* bsum    = colA + N_EDGES;

  const int NB = (N_NODES + 255) / 256;

  hipMemsetAsync(deg, 0, sizeof(int) * 2 * N_NODES, stream);
  hipMemsetAsync(stats, 0, sizeof(float) * 5 * STB, stream);  // all layers at once

  prep_kernel<<<(TOT_PAIRS + 255) / 256, 256, 0, stream>>>(W_pre, cWl, cWr, cWres, c5Wl, c5Wr, wph);
  cnt_bsearch_kernel<<<1, 64, 0, stream>>>(batch, cntInt);
  deg_hist_kernel<<<(N_EDGES + 255) / 256, 256, 0, stream>>>(dstE, deg);
  scan1_kernel<<<NB, 256, 0, stream>>>(deg, bsum);
  scan2_kernel<<<1, 256, 0, stream>>>(bsum, NB);
  scan3_kernel<<<NB, 256, 0, stream>>>(deg, bsum, rowptr);
  scatter_kernel<<<(N_EDGES + 255) / 256, 256, 0, stream>>>(srcE, dstE, rowptr, fill, colA);

  const int GNB = (N_NODES + 63) / 64;  // 782 blocks for gn_stats

  // pre: buf0 = x @ W_pre + b_pre  (raw, no norm on input)
  gemm_mfma<<<GX8 * 1 * 8, 256, 0, stream>>>(x, N_NODES, IN_F, 4, 1, wph, 0,
                                             nullptr, nullptr,
                                             b_pre, nullptr, nullptr,
                                             buf0, nullptr, nullptr);
  gn_stats_kernel<<<GNB, 256, 0, stream>>>(buf0, batch, stats);
  gn_finalize_kernel<<<(NGRAPH * HC + 255) / 256, 256, 0, stream>>>(stats, cntInt, gn_w, gn_b, gn_ms, 0, scsh);

  float* h = buf0;  // raw buffer; norm applied on the fly by consumers
  float* o = buf3;
  for (int i = 0; i < 4; i++) {
    const _Float16* Wcat_i = wph + PREH + (size_t)(3 * i) * MATH;
    gemm_mfma<<<GX8 * 3 * 8, 256, 0, stream>>>(h, N_NODES, HC, 6, 3, Wcat_i, MATH,
                                               scsh, batch,
                                               nullptr, nullptr, cB + i * HC,
                                               buf1, buf2, o);
    attn_concat_kernel<<<(N_NODES + 3) / 4, 256, 0, stream>>>(buf1, buf2, cAtt + i * HC, rowptr, colA, o);
    float* st = stats + (size_t)(i + 1) * STB;
    gn_stats_kernel<<<GNB, 256, 0, stream>>>(o, batch, st);
    gn_finalize_kernel<<<(NGRAPH * HC + 255) / 256, 256, 0, stream>>>(st, cntInt, gn_w, gn_b, gn_ms, i + 1, scsh);
    float* tmp = h; h = o; o = tmp;
  }

  // conv5 (input = raw h with scsh row 4 fused in consumers)
  const _Float16* Wc5 = wph + PREH + (size_t)12 * MATH;
  gemm_mfma<<<GX8 * 2 * 8, 256, 0, stream>>>(h, N_NODES, HC, 6, 2, Wc5, MATH,
                                             scsh, batch,
                                             nullptr, nullptr, nullptr,
                                             buf1, buf2, nullptr);
  res16_kernel<<<N_NODES / 16, 256, 0, stream>>>(h, scsh, batch, c5Wres, c5b, res16);
  attn_mean_kernel<<<(N_NODES + 3) / 4, 256, 0, stream>>>(buf1, buf2, c5Att, rowptr, colA, res16, out16);

  head_kernel<<<NB, 256, 0, stream>>>(out16, Wo1, bo1, Wo2, bo2, Wc, bc, (float*)d_out);
}

// Round 14
// 836.184 us; speedup vs baseline: 1.0265x; 1.0253x over previous
//
#include <hip/hip_runtime.h>
#include <math.h>

#define N_NODES 50000
#define N_EDGES 400000
#define IN_F 128
#define HC 176
#define NGRAPH 64
#define NBLK_ATTN 12500   // N_NODES/4 exactly

typedef _Float16 half8 __attribute__((ext_vector_type(8)));
typedef float floatx4 __attribute__((ext_vector_type(4)));

// =====================================================================
// Packed split-fp16 weights in MFMA B-fragment order.
// =====================================================================
#define PREH 45056   // 4*11*2*512 halves
#define MATH 67584   // 6*11*2*512 halves
#define TOT_PAIRS 495616  // 22528 + 14*33792
#define KCBYTES 22528     // bytes per kc chunk (11*2*512*2)
#define GX8 49            // row-tile groups of 8 (49*8=392 >= 391 tiles)

__global__ void prep_kernel(const float* __restrict__ Wpre,
                            const float* __restrict__ cWl, const float* __restrict__ cWr,
                            const float* __restrict__ cWres,
                            const float* __restrict__ c5Wl, const float* __restrict__ c5Wr,
                            _Float16* __restrict__ wp) {
  int gid = blockIdx.x * 256 + threadIdx.x;
  if (gid >= TOT_PAIRS) return;
  int mat, idx;
  if (gid < 22528) { mat = 0; idx = gid; }
  else { int g = gid - 22528; mat = 1 + g / 33792; idx = g % 33792; }
  int kc = idx / 5632;
  int rem = idx - kc * 5632;
  int ct = rem / 512;
  int li = rem - ct * 512;
  int lane = li >> 3, j = li & 7;
  int k = kc * 32 + ((lane >> 4) << 3) + j;
  int col = ct * 16 + (lane & 15);
  const float* src; int Ksrc; size_t base;
  if (mat == 0) { src = Wpre; Ksrc = 128; base = 0; }
  else if (mat <= 12) {
    int lm = mat - 1; int layer = lm / 3; int sub = lm - layer * 3;
    const float* s = (sub == 0) ? cWl : (sub == 1) ? cWr : cWres;
    src = s + (size_t)layer * HC * HC; Ksrc = HC;
    base = PREH + (size_t)lm * MATH;
  } else {
    src = (mat == 13) ? c5Wl : c5Wr; Ksrc = HC;
    base = PREH + (size_t)12 * MATH + (size_t)(mat - 13) * MATH;
  }
  float v = (k < Ksrc) ? src[(size_t)k * HC + col] : 0.0f;
  _Float16 h = (_Float16)v;
  _Float16 l = (_Float16)(v - (float)h);
  size_t o = base + (size_t)(kc * 11 + ct) * 1024 + li;
  wp[o] = h;
  wp[o + 512] = l;
}

// =====================================================================
// Split-fp16 MFMA GEMM with block-level LDS staging of B (R7) + XCD
// swizzle (R8). grid.x = GX8 * nmat * 8.
// =====================================================================
__global__ __launch_bounds__(256, 2) void gemm_mfma(
    const float* __restrict__ A, int M, int K, int nkc, int nmat,
    const _Float16* __restrict__ Wp, int matStride,
    const float* __restrict__ scsh, const int* __restrict__ batch,
    const float* __restrict__ bias0, const float* __restrict__ bias1,
    const float* __restrict__ bias2,
    float* __restrict__ out0, float* __restrict__ out1, float* __restrict__ out2) {
  __shared__ __align__(16) char smem[2 * KCBYTES];
  const int b = blockIdx.x;
  const int grp = b >> 3, sub = b & 7;
  const int mat = grp % nmat;
  const int tile = ((grp / nmat) << 3) | sub;
  if (tile * 128 >= M) return;
  const _Float16* W = Wp + (size_t)mat * matStride;
  float* outp = (mat == 0) ? out0 : (mat == 1) ? out1 : out2;
  const float* bias = (mat == 0) ? bias0 : (mat == 1) ? bias1 : bias2;
  const int tid = threadIdx.x;
  const int lane = tid & 63;
  const int wv = tid >> 6;
  const int m16 = lane & 15, quad = lane >> 4;
  const int kb = quad << 3;
  const int rowBase = tile * 128 + wv * 32;
  const int rA0 = min(rowBase + m16, M - 1);
  const int rA1 = min(rowBase + 16 + m16, M - 1);
  const float* ap0 = A + (size_t)rA0 * K + kb;
  const float* ap1 = A + (size_t)rA1 * K + kb;
  const float* sc0 = nullptr; const float* sh0 = nullptr;
  const float* sc1 = nullptr; const float* sh1 = nullptr;
  if (scsh) {
    int g0 = batch[rA0], g1 = batch[rA1];
    sc0 = scsh + (size_t)g0 * HC + kb;
    sh0 = scsh + (size_t)(NGRAPH + g0) * HC + kb;
    sc1 = scsh + (size_t)g1 * HC + kb;
    sh1 = scsh + (size_t)(NGRAPH + g1) * HC + kb;
  }

  auto stage = [&](int kc, int buf) {
    const char* src = (const char*)W + (size_t)kc * KCBYTES;
    char* dst = smem + buf * KCBYTES;
#pragma unroll
    for (int i = 0; i < 6; i++) {
      int idx = wv * 6 + i;
      if (idx < 22) {
        __builtin_amdgcn_global_load_lds(
            (const __attribute__((address_space(1))) unsigned int*)(src + idx * 1024 + lane * 16),
            (__attribute__((address_space(3))) unsigned int*)(dst + idx * 1024),
            16, 0, 0);
      }
    }
  };

  floatx4 acc0[11], acc1[11];
#pragma unroll
  for (int ct = 0; ct < 11; ct++)
#pragma unroll
    for (int r = 0; r < 4; r++) { acc0[ct][r] = 0.0f; acc1[ct][r] = 0.0f; }

  stage(0, 0);

  for (int kc = 0; kc < nkc; kc++) {
    const int buf = kc & 1;
    __syncthreads();
    if (kc + 1 < nkc) stage(kc + 1, 1 - buf);

    const int koff = kc << 5;
    float va0[8], va1[8];
    if (koff + kb + 8 <= K) {
      float4 u0 = *(const float4*)(ap0 + koff);
      float4 u1 = *(const float4*)(ap0 + koff + 4);
      float4 w0 = *(const float4*)(ap1 + koff);
      float4 w1 = *(const float4*)(ap1 + koff + 4);
      va0[0] = u0.x; va0[1] = u0.y; va0[2] = u0.z; va0[3] = u0.w;
      va0[4] = u1.x; va0[5] = u1.y; va0[6] = u1.z; va0[7] = u1.w;
      va1[0] = w0.x; va1[1] = w0.y; va1[2] = w0.z; va1[3] = w0.w;
      va1[4] = w1.x; va1[5] = w1.y; va1[6] = w1.z; va1[7] = w1.w;
      if (scsh) {
        float s0[8], h0[8], s1[8], h1[8];
        float4 t;
        t = *(const float4*)(sc0 + koff);     s0[0]=t.x; s0[1]=t.y; s0[2]=t.z; s0[3]=t.w;
        t = *(const float4*)(sc0 + koff + 4); s0[4]=t.x; s0[5]=t.y; s0[6]=t.z; s0[7]=t.w;
        t = *(const float4*)(sh0 + koff);     h0[0]=t.x; h0[1]=t.y; h0[2]=t.z; h0[3]=t.w;
        t = *(const float4*)(sh0 + koff + 4); h0[4]=t.x; h0[5]=t.y; h0[6]=t.z; h0[7]=t.w;
        t = *(const float4*)(sc1 + koff);     s1[0]=t.x; s1[1]=t.y; s1[2]=t.z; s1[3]=t.w;
        t = *(const float4*)(sc1 + koff + 4); s1[4]=t.x; s1[5]=t.y; s1[6]=t.z; s1[7]=t.w;
        t = *(const float4*)(sh1 + koff);     h1[0]=t.x; h1[1]=t.y; h1[2]=t.z; h1[3]=t.w;
        t = *(const float4*)(sh1 + koff + 4); h1[4]=t.x; h1[5]=t.y; h1[6]=t.z; h1[7]=t.w;
#pragma unroll
        for (int j = 0; j < 8; j++) {
          va0[j] = fmaxf(fmaf(va0[j], s0[j], h0[j]), 0.0f);
          va1[j] = fmaxf(fmaf(va1[j], s1[j], h1[j]), 0.0f);
        }
      }
    } else {
#pragma unroll
      for (int j = 0; j < 8; j++) { va0[j] = 0.0f; va1[j] = 0.0f; }
    }
    half8 ah0, al0, ah1, al1;
#pragma unroll
    for (int j = 0; j < 8; j++) {
      _Float16 h = (_Float16)va0[j];
      ah0[j] = h; al0[j] = (_Float16)(va0[j] - (float)h);
      _Float16 g = (_Float16)va1[j];
      ah1[j] = g; al1[j] = (_Float16)(va1[j] - (float)g);
    }
    const char* bbase = smem + buf * KCBYTES + lane * 16;
#pragma unroll
    for (int ct = 0; ct < 11; ct++) {
      half8 bh = *(const half8*)(bbase + ct * 2048);
      half8 bl = *(const half8*)(bbase + ct * 2048 + 1024);
      acc0[ct] = __builtin_amdgcn_mfma_f32_16x16x32_f16(ah0, bh, acc0[ct], 0, 0, 0);
      acc1[ct] = __builtin_amdgcn_mfma_f32_16x16x32_f16(ah1, bh, acc1[ct], 0, 0, 0);
      acc0[ct] = __builtin_amdgcn_mfma_f32_16x16x32_f16(al0, bh, acc0[ct], 0, 0, 0);
      acc1[ct] = __builtin_amdgcn_mfma_f32_16x16x32_f16(al1, bh, acc1[ct], 0, 0, 0);
      acc0[ct] = __builtin_amdgcn_mfma_f32_16x16x32_f16(ah0, bl, acc0[ct], 0, 0, 0);
      acc1[ct] = __builtin_amdgcn_mfma_f32_16x16x32_f16(ah1, bl, acc1[ct], 0, 0, 0);
    }
  }

  float bv[11];
#pragma unroll
  for (int ct = 0; ct < 11; ct++) bv[ct] = bias ? bias[ct * 16 + m16] : 0.0f;
#pragma unroll
  for (int r = 0; r < 4; r++) {
    int row0 = rowBase + (quad << 2) + r;
    if (row0 < M) {
      float* op = outp + (size_t)row0 * HC + m16;
#pragma unroll
      for (int ct = 0; ct < 11; ct++) op[ct * 16] = acc0[ct][r] + bv[ct];
    }
    int row1 = row0 + 16;
    if (row1 < M) {
      float* op = outp + (size_t)row1 * HC + m16;
#pragma unroll
      for (int ct = 0; ct < 11; ct++) op[ct * 16] = acc1[ct][r] + bv[ct];
    }
  }
}

// =====================================================================
// GraphNorm stats for layer 0 only (R13 vectorized form).
// =====================================================================
__global__ __launch_bounds__(256) void gn_stats_kernel(const float* __restrict__ h,
                                                       const int* __restrict__ batch,
                                                       float* __restrict__ stats) {
  int t = threadIdx.x;
  int wv = t >> 6, lane = t & 63;
  if (lane >= 44) return;
  int n0 = blockIdx.x * 64 + wv * 16;
  if (n0 >= N_NODES) return;
  int n1 = min(n0 + 16, N_NODES);
  int f4 = lane * 4;
  float4 s = make_float4(0.f, 0.f, 0.f, 0.f);
  float4 ss = make_float4(0.f, 0.f, 0.f, 0.f);
  int gcur = batch[n0];
  for (int n = n0; n < n1; n++) {
    int g = batch[n];
    if (g != gcur) {
      float* sp = stats + (size_t)gcur * HC + f4;
      float* qp = stats + (size_t)(NGRAPH + gcur) * HC + f4;
      atomicAdd(sp + 0, s.x); atomicAdd(sp + 1, s.y);
      atomicAdd(sp + 2, s.z); atomicAdd(sp + 3, s.w);
      atomicAdd(qp + 0, ss.x); atomicAdd(qp + 1, ss.y);
      atomicAdd(qp + 2, ss.z); atomicAdd(qp + 3, ss.w);
      s = make_float4(0.f, 0.f, 0.f, 0.f);
      ss = make_float4(0.f, 0.f, 0.f, 0.f);
      gcur = g;
    }
    float4 v = *(const float4*)(h + (size_t)n * HC + f4);
    s.x += v.x; s.y += v.y; s.z += v.z; s.w += v.w;
    ss.x = fmaf(v.x, v.x, ss.x); ss.y = fmaf(v.y, v.y, ss.y);
    ss.z = fmaf(v.z, v.z, ss.z); ss.w = fmaf(v.w, v.w, ss.w);
  }
  float* sp = stats + (size_t)gcur * HC + f4;
  float* qp = stats + (size_t)(NGRAPH + gcur) * HC + f4;
  atomicAdd(sp + 0, s.x); atomicAdd(sp + 1, s.y);
  atomicAdd(sp + 2, s.z); atomicAdd(sp + 3, s.w);
  atomicAdd(qp + 0, ss.x); atomicAdd(qp + 1, ss.y);
  atomicAdd(qp + 2, ss.z); atomicAdd(qp + 3, ss.w);
}

// =====================================================================
// Reduce per-block partials (written by attn_concat) into stats.
// Graph g owns contiguous blocks [(gstart[g]+3)>>2, (gstart[g+1]+3)>>2);
// 4-way chunk split for parallelism; ~90k atomics total.
// =====================================================================
__global__ __launch_bounds__(256) void part_reduce_kernel(
    const float* __restrict__ parts, const float* __restrict__ partq,
    const int* __restrict__ gstart, float* __restrict__ stats) {
  int idx = blockIdx.x * 256 + threadIdx.x;
  if (idx >= NGRAPH * 4 * HC) return;
  int f = idx % HC;
  int gc = idx / HC;
  int g = gc >> 2, c = gc & 3;
  int s0 = gstart[g], s1 = gstart[g + 1];
  int b0 = (s0 + 3) >> 2, b1 = (s1 + 3) >> 2;
  int len = b1 - b0;
  if (len <= 0) return;
  int per = (len + 3) >> 2;
  int cb0 = b0 + c * per;
  int cb1 = min(cb0 + per, b1);
  if (cb0 >= cb1) return;
  float s = 0.f, ss = 0.f;
  for (int b = cb0; b < cb1; b++) {
    s += parts[(size_t)b * HC + f];
    ss += partq[(size_t)b * HC + f];
  }
  atomicAdd(&stats[g * HC + f], s);
  atomicAdd(&stats[(NGRAPH + g) * HC + f], ss);
}

__global__ void gn_finalize_kernel(const float* __restrict__ stats, const int* __restrict__ cntInt,
                                   const float* __restrict__ gnw, const float* __restrict__ gnb,
                                   const float* __restrict__ gnms, int row,
                                   float* __restrict__ scsh) {
  int i = blockIdx.x * 256 + threadIdx.x;
  if (i >= NGRAPH * HC) return;
  int g = i / HC, f = i - g * HC;
  float c = fmaxf((float)cntInt[g], 1.0f);
  float m = stats[i] / c;
  float sq = stats[NGRAPH * HC + i] / c;
  float ms = gnms[row * HC + f];
  float var = sq - m * m * ms * (2.0f - ms);
  float w = gnw[row * HC + f], b = gnb[row * HC + f];
  float scale = w / sqrtf(var + 1e-5f);
  float shift = b - scale * ms * m;
  scsh[i] = scale;
  scsh[NGRAPH * HC + i] = shift;
}

// =====================================================================
// Per-graph counts + start offsets via binary search (batch sorted).
// =====================================================================
__global__ void cnt_bsearch_kernel(const int* __restrict__ batch, int* __restrict__ cntInt,
                                   int* __restrict__ gstart) {
  int g = threadIdx.x;
  if (g >= NGRAPH) return;
  auto lb = [&](int v) {
    int lo = 0, hi = N_NODES;
    while (lo < hi) {
      int mid = (lo + hi) >> 1;
      if (batch[mid] < v) lo = mid + 1; else hi = mid;
    }
    return lo;
  };
  int a = lb(g), b = lb(g + 1);
  cntInt[g] = b - a;
  gstart[g] = a;
  if (g == NGRAPH - 1) gstart[NGRAPH] = N_NODES;
}

// =====================================================================
// CSR build by destination
// =====================================================================
__global__ void deg_hist_kernel(const int* __restrict__ dstE, int* __restrict__ deg) {
  int e = blockIdx.x * 256 + threadIdx.x;
  if (e < N_EDGES) atomicAdd(&deg[dstE[e]], 1);
}

__global__ void scan1_kernel(const int* __restrict__ deg, int* __restrict__ bsum) {
  __shared__ int sd[256];
  int i = blockIdx.x * 256 + threadIdx.x;
  sd[threadIdx.x] = (i < N_NODES) ? deg[i] : 0;
  __syncthreads();
  for (int s = 128; s > 0; s >>= 1) {
    if (threadIdx.x < s) sd[threadIdx.x] += sd[threadIdx.x + s];
    __syncthreads();
  }
  if (threadIdx.x == 0) bsum[blockIdx.x] = sd[0];
}

__global__ void scan2_kernel(int* __restrict__ bsum, int nb) {
  __shared__ int sd[256];
  int t = threadIdx.x;
  int v0 = (t < nb) ? bsum[t] : 0;
  sd[t] = v0;
  __syncthreads();
  for (int s = 1; s < 256; s <<= 1) {
    int v = (t >= s) ? sd[t - s] : 0;
    __syncthreads();
    sd[t] += v;
    __syncthreads();
  }
  if (t < nb) bsum[t] = sd[t] - v0;  // exclusive
}

__global__ void scan3_kernel(const int* __restrict__ deg, const int* __restrict__ bsum,
                             int* __restrict__ rowptr) {
  __shared__ int sd[256];
  int i = blockIdx.x * 256 + threadIdx.x;
  int t = threadIdx.x;
  int d = (i < N_NODES) ? deg[i] : 0;
  sd[t] = d;
  __syncthreads();
  for (int s = 1; s < 256; s <<= 1) {
    int v = (t >= s) ? sd[t - s] : 0;
    __syncthreads();
    sd[t] += v;
    __syncthreads();
  }
  if (i < N_NODES) rowptr[i] = bsum[blockIdx.x] + sd[t] - d;
  if (i == 0) rowptr[N_NODES] = N_EDGES;
}

__global__ void scatter_kernel(const int* __restrict__ srcE, const int* __restrict__ dstE,
                               const int* __restrict__ rowptr, int* __restrict__ fill,
                               int* __restrict__ colA) {
  int e = blockIdx.x * 256 + threadIdx.x;
  if (e < N_EDGES) {
    int d = dstE[e];
    int pos = rowptr[d] + atomicAdd(&fill[d], 1);
    colA[pos] = srcE[e];
  }
}

// =====================================================================
// GATv2 attention (R9 main body) + GraphNorm stats fused via per-block
// PARTIAL ARRAYS (non-atomic coalesced stores); only graph-straddling
// nodes (~63 blocks) use atomics. Replaces R11's 4.4M-atomic scheme.
// =====================================================================
#define AEDGE(V, D, ACC)                                                      \
  do {                                                                        \
    float e0 = (V).x + xrv.x; e0 = fmaxf(e0, 0.2f * e0);                      \
    float e1 = (V).y + xrv.y; e1 = fmaxf(e1, 0.2f * e1);                      \
    float e2 = (V).z + xrv.z; e2 = fmaxf(e2, 0.2f * e2);                      \
    float e3 = (V).w + xrv.w; e3 = fmaxf(e3, 0.2f * e3);                      \
    float p = fmaf(e3, av.w, fmaf(e2, av.z, fmaf(e1, av.y, e0 * av.x)));      \
    p += __shfl_xor(p, 1);                                                    \
    p += __shfl_xor(p, 2);                                                    \
    float pp = __expf(p);                                                     \
    (D) += pp;                                                                \
    (ACC).x = fmaf(pp, (V).x, (ACC).x);                                       \
    (ACC).y = fmaf(pp, (V).y, (ACC).y);                                       \
    (ACC).z = fmaf(pp, (V).z, (ACC).z);                                       \
    (ACC).w = fmaf(pp, (V).w, (ACC).w);                                       \
  } while (0)

__global__ __launch_bounds__(256) void attn_concat_kernel(
    const float* __restrict__ xl, const float* __restrict__ xr,
    const float* __restrict__ att, const int* __restrict__ rowptr,
    const int* __restrict__ colA, float* __restrict__ out,
    const int* __restrict__ batch, float* __restrict__ stats,
    float* __restrict__ parts, float* __restrict__ partq) {
  __shared__ float sv[4 * HC];
  int t = threadIdx.x;
  int node = blockIdx.x * 4 + (t >> 6);
  int lane = t & 63;
  if (lane < 44) {  // node < N always (grid = N/4 exactly)
    const float4 av = *(const float4*)(att + lane * 4);
    size_t base = (size_t)node * HC + lane * 4;
    const float4 xrv = *(const float4*)(xr + base);
    int start = rowptr[node], end = rowptr[node + 1];
    float d = 0.0f, dB = 0.0f;
    float4 acc = make_float4(0.f, 0.f, 0.f, 0.f);
    float4 accB = make_float4(0.f, 0.f, 0.f, 0.f);
    float4 p1, p2;
    if (start < end)     p1 = *(const float4*)(xl + (size_t)colA[start] * HC + lane * 4);
    if (start + 1 < end) p2 = *(const float4*)(xl + (size_t)colA[start + 1] * HC + lane * 4);
    {
      float4 svv = *(const float4*)(xl + base);  // self-loop
      AEDGE(svv, d, acc);
    }
    int j = start;
    for (; j + 3 < end; j += 2) {
      float4 n1 = *(const float4*)(xl + (size_t)colA[j + 2] * HC + lane * 4);
      float4 n2 = *(const float4*)(xl + (size_t)colA[j + 3] * HC + lane * 4);
      AEDGE(p1, d, acc);
      AEDGE(p2, dB, accB);
      p1 = n1; p2 = n2;
    }
    if (j < end)     AEDGE(p1, d, acc);
    if (j + 1 < end) AEDGE(p2, dB, accB);
    if (j + 2 < end) {
      float4 n1 = *(const float4*)(xl + (size_t)colA[j + 2] * HC + lane * 4);
      AEDGE(n1, d, acc);
    }
    d += dB;
    acc.x += accB.x; acc.y += accB.y; acc.z += accB.z; acc.w += accB.w;
    float rd = 1.0f / (d + 1e-16f);
    float4 o = *(const float4*)(out + base);  // residual+bias already there
    o.x = fmaf(acc.x, rd, o.x);
    o.y = fmaf(acc.y, rd, o.y);
    o.z = fmaf(acc.z, rd, o.z);
    o.w = fmaf(acc.w, rd, o.w);
    *(float4*)(out + base) = o;
    *(float4*)(&sv[(t >> 6) * HC + lane * 4]) = o;
  }
  __syncthreads();
  if (t < HC) {
    int b = blockIdx.x;
    int g0 = batch[b * 4];
    float s = 0.0f, ss = 0.0f;
#pragma unroll
    for (int w = 0; w < 4; w++) {
      int g = batch[b * 4 + w];
      float v = sv[w * HC + t];
      if (g == g0) {
        s += v;
        ss = fmaf(v, v, ss);
      } else {  // rare graph-straddle: direct atomic
        atomicAdd(&stats[g * HC + t], v);
        atomicAdd(&stats[(NGRAPH + g) * HC + t], v * v);
      }
    }
    parts[(size_t)b * HC + t] = s;
    partq[(size_t)b * HC + t] = ss;
  }
}

__global__ __launch_bounds__(256) void attn_mean_kernel(
    const float* __restrict__ xl, const float* __restrict__ xr,
    const float* __restrict__ att, const int* __restrict__ rowptr,
    const int* __restrict__ colA, const float* __restrict__ res16,
    float* __restrict__ out16) {
  int t = threadIdx.x;
  int node = blockIdx.x * 4 + (t >> 6);
  int lane = t & 63;
  if (node >= N_NODES) return;
  int L = (lane < 44) ? lane : 0;  // lanes 44..63 ride along (zeroed later)
  const float4 av = *(const float4*)(att + L * 4);
  size_t base = (size_t)node * HC + L * 4;
  const float4 xrv = *(const float4*)(xr + base);
  int start = rowptr[node], end = rowptr[node + 1];
  float d = 0.0f, dB = 0.0f;
  float4 acc = make_float4(0.f, 0.f, 0.f, 0.f);
  float4 accB = make_float4(0.f, 0.f, 0.f, 0.f);
  float4 p1, p2;
  if (start < end)     p1 = *(const float4*)(xl + (size_t)colA[start] * HC + L * 4);
  if (start + 1 < end) p2 = *(const float4*)(xl + (size_t)colA[start + 1] * HC + L * 4);
  {
    float4 sv = *(const float4*)(xl + base);
    AEDGE(sv, d, acc);
  }
  int j = start;
  for (; j + 3 < end; j += 2) {
    float4 n1 = *(const float4*)(xl + (size_t)colA[j + 2] * HC + L * 4);
    float4 n2 = *(const float4*)(xl + (size_t)colA[j + 3] * HC + L * 4);
    AEDGE(p1, d, acc);
    AEDGE(p2, dB, accB);
    p1 = n1; p2 = n2;
  }
  if (j < end)     AEDGE(p1, d, acc);
  if (j + 1 < end) AEDGE(p2, dB, accB);
  if (j + 2 < end) {
    float4 n1 = *(const float4*)(xl + (size_t)colA[j + 2] * HC + L * 4);
    AEDGE(n1, d, acc);
  }
  d += dB;
  acc.x += accB.x; acc.y += accB.y; acc.z += accB.z; acc.w += accB.w;
  float rd = 1.0f / (d + 1e-16f);
  float4 o;
  o.x = (lane < 44) ? acc.x * rd : 0.0f;
  o.y = (lane < 44) ? acc.y * rd : 0.0f;
  o.z = (lane < 44) ? acc.z * rd : 0.0f;
  o.w = (lane < 44) ? acc.w * rd : 0.0f;
#pragma unroll
  for (int w = 4; w <= 32; w <<= 1) {
    o.x += __shfl_xor(o.x, w);
    o.y += __shfl_xor(o.y, w);
    o.z += __shfl_xor(o.z, w);
    o.w += __shfl_xor(o.w, w);
  }
  if (lane < 4) {
    const float* rp = res16 + (size_t)node * 16 + lane * 4;
    float4 r = *(const float4*)rp;
    float4 ov;
    ov.x = fmaxf(fmaf(o.x, 1.0f / 11.0f, r.x), 0.0f);
    ov.y = fmaxf(fmaf(o.y, 1.0f / 11.0f, r.y), 0.0f);
    ov.z = fmaxf(fmaf(o.z, 1.0f / 11.0f, r.z), 0.0f);
    ov.w = fmaxf(fmaf(o.w, 1.0f / 11.0f, r.w), 0.0f);
    *(float4*)(out16 + (size_t)node * 16 + lane * 4) = ov;
  }
}

// =====================================================================
// res16 = normApply(h) @ c5_Wres(176x16) + c5_b   (norm+relu fused in load)
// =====================================================================
__global__ __launch_bounds__(256) void res16_kernel(const float* __restrict__ h,
                                                    const float* __restrict__ scsh,
                                                    const int* __restrict__ batch,
                                                    const float* __restrict__ Wres,
                                                    const float* __restrict__ b16,
                                                    float* __restrict__ res16) {
  __shared__ float Ws[176 * 16];
  __shared__ float hs[16 * 176];
  int t = threadIdx.x;
  for (int i = t; i < 176 * 16; i += 256) Ws[i] = Wres[i];
  int n0 = blockIdx.x * 16;
  for (int i = t; i < 16 * 176; i += 256) {
    int row = i / 176, k = i - row * 176;
    int g = batch[n0 + row];
    float v = h[(size_t)n0 * HC + i];
    hs[i] = fmaxf(fmaf(v, scsh[g * HC + k], scsh[(NGRAPH + g) * HC + k]), 0.0f);
  }
  __syncthreads();
  int tx = t & 15, ty = t >> 4;
  float acc = b16[tx];
  for (int k = 0; k < HC; k++) acc = fmaf(hs[ty * HC + k], Ws[k * 16 + tx], acc);
  res16[(size_t)(n0 + ty) * 16 + tx] = acc;
}

// =====================================================================
// Head MLP
// =====================================================================
__global__ __launch_bounds__(256) void head_kernel(
    const float* __restrict__ in16, const float* __restrict__ Wo1,
    const float* __restrict__ bo1, const float* __restrict__ Wo2,
    const float* __restrict__ bo2, const float* __restrict__ Wc,
    const float* __restrict__ bc, float* __restrict__ outp) {
  __shared__ float w1[256], w2[512], wcS[320], b1[16], b2[32], bcS[10];
  int t = threadIdx.x;
  for (int i = t; i < 256; i += 256) w1[i] = Wo1[i];
  for (int i = t; i < 512; i += 256) w2[i] = Wo2[i];
  for (int i = t; i < 320; i += 256) wcS[i] = Wc[i];
  if (t < 16) b1[t] = bo1[t];
  if (t < 32) b2[t] = bo2[t];
  if (t < 10) bcS[t] = bc[t];
  __syncthreads();
  int n = blockIdx.x * 256 + t;
  if (n >= N_NODES) return;
  float x[16];
#pragma unroll
  for (int i = 0; i < 16; i++) x[i] = in16[(size_t)n * 16 + i];
  float o1[16];
#pragma unroll
  for (int j = 0; j < 16; j++) {
    float a = b1[j];
#pragma unroll
    for (int k = 0; k < 16; k++) a = fmaf(x[k], w1[k * 16 + j], a);
    o1[j] = fmaxf(a, 0.0f);
  }
  float o2[32];
#pragma unroll
  for (int j = 0; j < 32; j++) {
    float a = b2[j];
#pragma unroll
    for (int k = 0; k < 16; k++) a = fmaf(o1[k], w2[k * 32 + j], a);
    o2[j] = fmaxf(a, 0.0f);
  }
#pragma unroll
  for (int j = 0; j < 10; j++) {
    float a = bcS[j];
#pragma unroll
    for (int k = 0; k < 32; k++) a = fmaf(o2[k], wcS[k * 10 + j], a);
    outp[(size_t)n * 10 + j] = a;
  }
}

// =====================================================================
extern "C" void kernel_launch(void* const* d_in, const int* in_sizes, int n_in,
                              void* d_out, int out_size, void* d_ws, size_t ws_size,
                              hipStream_t stream) {
  (void)in_sizes; (void)n_in; (void)out_size; (void)ws_size;
  const float* x     = (const float*)d_in[0];
  const int*   ei    = (const int*)d_in[1];
  const int*   srcE  = ei;
  const int*   dstE  = ei + N_EDGES;
  const int*   batch = (const int*)d_in[2];
  const float* W_pre = (const float*)d_in[3];
  const float* b_pre = (const float*)d_in[4];
  const float* gn_w  = (const float*)d_in[5];
  const float* gn_b  = (const float*)d_in[6];
  const float* gn_ms = (const float*)d_in[7];
  const float* cWl   = (const float*)d_in[8];
  const float* cWr   = (const float*)d_in[9];
  const float* cAtt  = (const float*)d_in[10];
  const float* cB    = (const float*)d_in[11];
  const float* cWres = (const float*)d_in[12];
  const float* c5Wl  = (const float*)d_in[13];
  const float* c5Wr  = (const float*)d_in[14];
  const float* c5Att = (const float*)d_in[15];
  const float* c5b   = (const float*)d_in[16];
  const float* c5Wres= (const float*)d_in[17];
  const float* Wo1   = (const float*)d_in[18];
  const float* bo1   = (const float*)d_in[19];
  const float* Wo2   = (const float*)d_in[20];
  const float* bo2   = (const float*)d_in[21];
  const float* Wc    = (const float*)d_in[22];
  const float* bc    = (const float*)d_in[23];

  const size_t FB = (size_t)N_NODES * HC;
  const size_t STB = (size_t)2 * NGRAPH * HC;  // one stats buffer (22528 floats)
  const size_t PB = (size_t)NBLK_ATTN * HC;    // 2.2M floats per partial array
  float* ws    = (float*)d_ws;
  float* buf0  = ws;
  float* buf1  = ws + FB;
  float* buf2  = ws + 2 * FB;
  float* buf3  = ws + 3 * FB;
  float* res16 = ws + 4 * FB;
  float* out16 = res16 + (size_t)N_NODES * 16;
  float* stats = out16 + (size_t)N_NODES * 16;         // 5 buffers
  float* scsh  = stats + 5 * STB;
  float* parts = scsh + STB;
  float* partq = parts + PB;
  _Float16* wph = (_Float16*)(partq + PB);             // 991232 halves
  int* ibase   = (int*)((char*)wph + (size_t)991232 * 2);
  int* cntInt  = ibase;
  int* gstart  = ibase + 64;                           // 65 ints
  int* deg     = gstart + 65;
  int* fill    = deg + N_NODES;
  int* rowptr  = fill + N_NODES;
  int* colA    = rowptr + N_NODES + 1;
  int* bsum    = colA + N_EDGES;

  const int NB = (N_NODES + 255) / 256;

  hipMemsetAsync(deg, 0, sizeof(int) * 2 * N_NODES, stream);
  hipMemsetAsync(stats, 0, sizeof(float) * 5 * STB, stream);  // all layers at once

  prep_kernel<<<(TOT_PAIRS + 255) / 256, 256, 0, stream>>>(W_pre, cWl, cWr, cWres, c5Wl, c5Wr, wph);
  cnt_bsearch_kernel<<<1, 64, 0, stream>>>(batch, cntInt, gstart);
  deg_hist_kernel<<<(N_EDGES + 255) / 256, 256, 0, stream>>>(dstE, deg);
  scan1_kernel<<<NB, 256, 0, stream>>>(deg, bsum);
  scan2_kernel<<<1, 256, 0, stream>>>(bsum, NB);
  scan3_kernel<<<NB, 256, 0, stream>>>(deg, bsum, rowptr);
  scatter_kernel<<<(N_EDGES + 255) / 256, 256, 0, stream>>>(srcE, dstE, rowptr, fill, colA);

  const int GNB = (N_NODES + 63) / 64;  // 782 blocks for layer-0 gn_stats
  const int PRB = (NGRAPH * 4 * HC + 255) / 256;  // 176 blocks for part_reduce

  // pre: buf0 = x @ W_pre + b_pre  (raw, no norm on input)
  gemm_mfma<<<GX8 * 1 * 8, 256, 0, stream>>>(x, N_NODES, IN_F, 4, 1, wph, 0,
                                             nullptr, nullptr,
                                             b_pre, nullptr, nullptr,
                                             buf0, nullptr, nullptr);
  gn_stats_kernel<<<GNB, 256, 0, stream>>>(buf0, batch, stats);
  gn_finalize_kernel<<<(NGRAPH * HC + 255) / 256, 256, 0, stream>>>(stats, cntInt, gn_w, gn_b, gn_ms, 0, scsh);

  float* h = buf0;  // raw buffer; norm applied on the fly by consumers
  float* o = buf3;
  for (int i = 0; i < 4; i++) {
    const _Float16* Wcat_i = wph + PREH + (size_t)(3 * i) * MATH;
    gemm_mfma<<<GX8 * 3 * 8, 256, 0, stream>>>(h, N_NODES, HC, 6, 3, Wcat_i, MATH,
                                               scsh, batch,
                                               nullptr, nullptr, cB + i * HC,
                                               buf1, buf2, o);
    float* st = stats + (size_t)(i + 1) * STB;
    attn_concat_kernel<<<NBLK_ATTN, 256, 0, stream>>>(buf1, buf2, cAtt + i * HC,
                                                      rowptr, colA, o, batch, st,
                                                      parts, partq);
    part_reduce_kernel<<<PRB, 256, 0, stream>>>(parts, partq, gstart, st);
    gn_finalize_kernel<<<(NGRAPH * HC + 255) / 256, 256, 0, stream>>>(st, cntInt, gn_w, gn_b, gn_ms, i + 1, scsh);
    float* tmp = h; h = o; o = tmp;
  }

  // conv5 (input = raw h with scsh row 4 fused in consumers)
  const _Float16* Wc5 = wph + PREH + (size_t)12 * MATH;
  gemm_mfma<<<GX8 * 2 * 8, 256, 0, stream>>>(h, N_NODES, HC, 6, 2, Wc5, MATH,
                                             scsh, batch,
                                             nullptr, nullptr, nullptr,
                                             buf1, buf2, nullptr);
  res16_kernel<<<N_NODES / 16, 256, 0, stream>>>(h, scsh, batch, c5Wres, c5b, res16);
  attn_mean_kernel<<<(N_NODES + 3) / 4, 256, 0, stream>>>(buf1, buf2, c5Att, rowptr, colA, res16, out16);

  head_kernel<<<NB, 256, 0, stream>>>(out16, Wo1, bo1, Wo2, bo2, Wc, bc, (float*)d_out);
}

// Round 15
// 798.182 us; speedup vs baseline: 1.0753x; 1.0476x over previous
//
#include <hip/hip_runtime.h>
#include <math.h>

#define N_NODES 50000
#define N_EDGES 400000
#define IN_F 128
#define HC 176
#define NGRAPH 64
#define NBLK_ATTN 12500   // N_NODES/4 exactly
#define NCHUNK 16         // part_reduce chunks per graph

typedef _Float16 half8 __attribute__((ext_vector_type(8)));
typedef float floatx4 __attribute__((ext_vector_type(4)));

// =====================================================================
// Packed split-fp16 weights in MFMA B-fragment order.
// =====================================================================
#define PREH 45056   // 4*11*2*512 halves
#define MATH 67584   // 6*11*2*512 halves
#define TOT_PAIRS 495616  // 22528 + 14*33792
#define KCBYTES 22528     // bytes per kc chunk (11*2*512*2)
#define GX8 49            // row-tile groups of 8 (49*8=392 >= 391 tiles)

__global__ void prep_kernel(const float* __restrict__ Wpre,
                            const float* __restrict__ cWl, const float* __restrict__ cWr,
                            const float* __restrict__ cWres,
                            const float* __restrict__ c5Wl, const float* __restrict__ c5Wr,
                            _Float16* __restrict__ wp) {
  int gid = blockIdx.x * 256 + threadIdx.x;
  if (gid >= TOT_PAIRS) return;
  int mat, idx;
  if (gid < 22528) { mat = 0; idx = gid; }
  else { int g = gid - 22528; mat = 1 + g / 33792; idx = g % 33792; }
  int kc = idx / 5632;
  int rem = idx - kc * 5632;
  int ct = rem / 512;
  int li = rem - ct * 512;
  int lane = li >> 3, j = li & 7;
  int k = kc * 32 + ((lane >> 4) << 3) + j;
  int col = ct * 16 + (lane & 15);
  const float* src; int Ksrc; size_t base;
  if (mat == 0) { src = Wpre; Ksrc = 128; base = 0; }
  else if (mat <= 12) {
    int lm = mat - 1; int layer = lm / 3; int sub = lm - layer * 3;
    const float* s = (sub == 0) ? cWl : (sub == 1) ? cWr : cWres;
    src = s + (size_t)layer * HC * HC; Ksrc = HC;
    base = PREH + (size_t)lm * MATH;
  } else {
    src = (mat == 13) ? c5Wl : c5Wr; Ksrc = HC;
    base = PREH + (size_t)12 * MATH + (size_t)(mat - 13) * MATH;
  }
  float v = (k < Ksrc) ? src[(size_t)k * HC + col] : 0.0f;
  _Float16 h = (_Float16)v;
  _Float16 l = (_Float16)(v - (float)h);
  size_t o = base + (size_t)(kc * 11 + ct) * 1024 + li;
  wp[o] = h;
  wp[o + 512] = l;
}

// =====================================================================
// Split-fp16 MFMA GEMM with block-level LDS staging of B (R7) + XCD
// swizzle (R8). grid.x = GX8 * nmat * 8.
// =====================================================================
__global__ __launch_bounds__(256, 2) void gemm_mfma(
    const float* __restrict__ A, int M, int K, int nkc, int nmat,
    const _Float16* __restrict__ Wp, int matStride,
    const float* __restrict__ scsh, const int* __restrict__ batch,
    const float* __restrict__ bias0, const float* __restrict__ bias1,
    const float* __restrict__ bias2,
    float* __restrict__ out0, float* __restrict__ out1, float* __restrict__ out2) {
  __shared__ __align__(16) char smem[2 * KCBYTES];
  const int b = blockIdx.x;
  const int grp = b >> 3, sub = b & 7;
  const int mat = grp % nmat;
  const int tile = ((grp / nmat) << 3) | sub;
  if (tile * 128 >= M) return;
  const _Float16* W = Wp + (size_t)mat * matStride;
  float* outp = (mat == 0) ? out0 : (mat == 1) ? out1 : out2;
  const float* bias = (mat == 0) ? bias0 : (mat == 1) ? bias1 : bias2;
  const int tid = threadIdx.x;
  const int lane = tid & 63;
  const int wv = tid >> 6;
  const int m16 = lane & 15, quad = lane >> 4;
  const int kb = quad << 3;
  const int rowBase = tile * 128 + wv * 32;
  const int rA0 = min(rowBase + m16, M - 1);
  const int rA1 = min(rowBase + 16 + m16, M - 1);
  const float* ap0 = A + (size_t)rA0 * K + kb;
  const float* ap1 = A + (size_t)rA1 * K + kb;
  const float* sc0 = nullptr; const float* sh0 = nullptr;
  const float* sc1 = nullptr; const float* sh1 = nullptr;
  if (scsh) {
    int g0 = batch[rA0], g1 = batch[rA1];
    sc0 = scsh + (size_t)g0 * HC + kb;
    sh0 = scsh + (size_t)(NGRAPH + g0) * HC + kb;
    sc1 = scsh + (size_t)g1 * HC + kb;
    sh1 = scsh + (size_t)(NGRAPH + g1) * HC + kb;
  }

  auto stage = [&](int kc, int buf) {
    const char* src = (const char*)W + (size_t)kc * KCBYTES;
    char* dst = smem + buf * KCBYTES;
#pragma unroll
    for (int i = 0; i < 6; i++) {
      int idx = wv * 6 + i;
      if (idx < 22) {
        __builtin_amdgcn_global_load_lds(
            (const __attribute__((address_space(1))) unsigned int*)(src + idx * 1024 + lane * 16),
            (__attribute__((address_space(3))) unsigned int*)(dst + idx * 1024),
            16, 0, 0);
      }
    }
  };

  floatx4 acc0[11], acc1[11];
#pragma unroll
  for (int ct = 0; ct < 11; ct++)
#pragma unroll
    for (int r = 0; r < 4; r++) { acc0[ct][r] = 0.0f; acc1[ct][r] = 0.0f; }

  stage(0, 0);

  for (int kc = 0; kc < nkc; kc++) {
    const int buf = kc & 1;
    __syncthreads();
    if (kc + 1 < nkc) stage(kc + 1, 1 - buf);

    const int koff = kc << 5;
    float va0[8], va1[8];
    if (koff + kb + 8 <= K) {
      float4 u0 = *(const float4*)(ap0 + koff);
      float4 u1 = *(const float4*)(ap0 + koff + 4);
      float4 w0 = *(const float4*)(ap1 + koff);
      float4 w1 = *(const float4*)(ap1 + koff + 4);
      va0[0] = u0.x; va0[1] = u0.y; va0[2] = u0.z; va0[3] = u0.w;
      va0[4] = u1.x; va0[5] = u1.y; va0[6] = u1.z; va0[7] = u1.w;
      va1[0] = w0.x; va1[1] = w0.y; va1[2] = w0.z; va1[3] = w0.w;
      va1[4] = w1.x; va1[5] = w1.y; va1[6] = w1.z; va1[7] = w1.w;
      if (scsh) {
        float s0[8], h0[8], s1[8], h1[8];
        float4 t;
        t = *(const float4*)(sc0 + koff);     s0[0]=t.x; s0[1]=t.y; s0[2]=t.z; s0[3]=t.w;
        t = *(const float4*)(sc0 + koff + 4); s0[4]=t.x; s0[5]=t.y; s0[6]=t.z; s0[7]=t.w;
        t = *(const float4*)(sh0 + koff);     h0[0]=t.x; h0[1]=t.y; h0[2]=t.z; h0[3]=t.w;
        t = *(const float4*)(sh0 + koff + 4); h0[4]=t.x; h0[5]=t.y; h0[6]=t.z; h0[7]=t.w;
        t = *(const float4*)(sc1 + koff);     s1[0]=t.x; s1[1]=t.y; s1[2]=t.z; s1[3]=t.w;
        t = *(const float4*)(sc1 + koff + 4); s1[4]=t.x; s1[5]=t.y; s1[6]=t.z; s1[7]=t.w;
        t = *(const float4*)(sh1 + koff);     h1[0]=t.x; h1[1]=t.y; h1[2]=t.z; h1[3]=t.w;
        t = *(const float4*)(sh1 + koff + 4); h1[4]=t.x; h1[5]=t.y; h1[6]=t.z; h1[7]=t.w;
#pragma unroll
        for (int j = 0; j < 8; j++) {
          va0[j] = fmaxf(fmaf(va0[j], s0[j], h0[j]), 0.0f);
          va1[j] = fmaxf(fmaf(va1[j], s1[j], h1[j]), 0.0f);
        }
      }
    } else {
#pragma unroll
      for (int j = 0; j < 8; j++) { va0[j] = 0.0f; va1[j] = 0.0f; }
    }
    half8 ah0, al0, ah1, al1;
#pragma unroll
    for (int j = 0; j < 8; j++) {
      _Float16 h = (_Float16)va0[j];
      ah0[j] = h; al0[j] = (_Float16)(va0[j] - (float)h);
      _Float16 g = (_Float16)va1[j];
      ah1[j] = g; al1[j] = (_Float16)(va1[j] - (float)g);
    }
    const char* bbase = smem + buf * KCBYTES + lane * 16;
#pragma unroll
    for (int ct = 0; ct < 11; ct++) {
      half8 bh = *(const half8*)(bbase + ct * 2048);
      half8 bl = *(const half8*)(bbase + ct * 2048 + 1024);
      acc0[ct] = __builtin_amdgcn_mfma_f32_16x16x32_f16(ah0, bh, acc0[ct], 0, 0, 0);
      acc1[ct] = __builtin_amdgcn_mfma_f32_16x16x32_f16(ah1, bh, acc1[ct], 0, 0, 0);
      acc0[ct] = __builtin_amdgcn_mfma_f32_16x16x32_f16(al0, bh, acc0[ct], 0, 0, 0);
      acc1[ct] = __builtin_amdgcn_mfma_f32_16x16x32_f16(al1, bh, acc1[ct], 0, 0, 0);
      acc0[ct] = __builtin_amdgcn_mfma_f32_16x16x32_f16(ah0, bl, acc0[ct], 0, 0, 0);
      acc1[ct] = __builtin_amdgcn_mfma_f32_16x16x32_f16(ah1, bl, acc1[ct], 0, 0, 0);
    }
  }

  float bv[11];
#pragma unroll
  for (int ct = 0; ct < 11; ct++) bv[ct] = bias ? bias[ct * 16 + m16] : 0.0f;
#pragma unroll
  for (int r = 0; r < 4; r++) {
    int row0 = rowBase + (quad << 2) + r;
    if (row0 < M) {
      float* op = outp + (size_t)row0 * HC + m16;
#pragma unroll
      for (int ct = 0; ct < 11; ct++) op[ct * 16] = acc0[ct][r] + bv[ct];
    }
    int row1 = row0 + 16;
    if (row1 < M) {
      float* op = outp + (size_t)row1 * HC + m16;
#pragma unroll
      for (int ct = 0; ct < 11; ct++) op[ct * 16] = acc1[ct][r] + bv[ct];
    }
  }
}

// =====================================================================
// GraphNorm stats for layer 0 only (R13 vectorized form).
// =====================================================================
__global__ __launch_bounds__(256) void gn_stats_kernel(const float* __restrict__ h,
                                                       const int* __restrict__ batch,
                                                       float* __restrict__ stats) {
  int t = threadIdx.x;
  int wv = t >> 6, lane = t & 63;
  if (lane >= 44) return;
  int n0 = blockIdx.x * 64 + wv * 16;
  if (n0 >= N_NODES) return;
  int n1 = min(n0 + 16, N_NODES);
  int f4 = lane * 4;
  float4 s = make_float4(0.f, 0.f, 0.f, 0.f);
  float4 ss = make_float4(0.f, 0.f, 0.f, 0.f);
  int gcur = batch[n0];
  for (int n = n0; n < n1; n++) {
    int g = batch[n];
    if (g != gcur) {
      float* sp = stats + (size_t)gcur * HC + f4;
      float* qp = stats + (size_t)(NGRAPH + gcur) * HC + f4;
      atomicAdd(sp + 0, s.x); atomicAdd(sp + 1, s.y);
      atomicAdd(sp + 2, s.z); atomicAdd(sp + 3, s.w);
      atomicAdd(qp + 0, ss.x); atomicAdd(qp + 1, ss.y);
      atomicAdd(qp + 2, ss.z); atomicAdd(qp + 3, ss.w);
      s = make_float4(0.f, 0.f, 0.f, 0.f);
      ss = make_float4(0.f, 0.f, 0.f, 0.f);
      gcur = g;
    }
    float4 v = *(const float4*)(h + (size_t)n * HC + f4);
    s.x += v.x; s.y += v.y; s.z += v.z; s.w += v.w;
    ss.x = fmaf(v.x, v.x, ss.x); ss.y = fmaf(v.y, v.y, ss.y);
    ss.z = fmaf(v.z, v.z, ss.z); ss.w = fmaf(v.w, v.w, ss.w);
  }
  float* sp = stats + (size_t)gcur * HC + f4;
  float* qp = stats + (size_t)(NGRAPH + gcur) * HC + f4;
  atomicAdd(sp + 0, s.x); atomicAdd(sp + 1, s.y);
  atomicAdd(sp + 2, s.z); atomicAdd(sp + 3, s.w);
  atomicAdd(qp + 0, ss.x); atomicAdd(qp + 1, ss.y);
  atomicAdd(qp + 2, ss.z); atomicAdd(qp + 3, ss.w);
}

// =====================================================================
// Reduce per-block partials into stats. NCHUNK=16 chunks per graph ->
// 704 blocks (>=2.7/CU), ~12 rows per thread, wave-coalesced reads,
// ~360k atomics (~2 us). R14's 4-chunk version was <1 block/CU, 26 us.
// =====================================================================
__global__ __launch_bounds__(256) void part_reduce_kernel(
    const float* __restrict__ parts, const float* __restrict__ partq,
    const int* __restrict__ gstart, float* __restrict__ stats) {
  int idx = blockIdx.x * 256 + threadIdx.x;
  if (idx >= NGRAPH * NCHUNK * HC) return;
  int f = idx % HC;
  int gc = idx / HC;
  int g = gc / NCHUNK, c = gc % NCHUNK;
  int s0 = gstart[g], s1 = gstart[g + 1];
  int b0 = (s0 + 3) >> 2, b1 = (s1 + 3) >> 2;
  int len = b1 - b0;
  if (len <= 0) return;
  int per = (len + NCHUNK - 1) / NCHUNK;
  int cb0 = b0 + c * per;
  int cb1 = min(cb0 + per, b1);
  if (cb0 >= cb1) return;
  float s = 0.f, ss = 0.f;
  for (int b = cb0; b < cb1; b++) {
    s += parts[(size_t)b * HC + f];
    ss += partq[(size_t)b * HC + f];
  }
  atomicAdd(&stats[g * HC + f], s);
  atomicAdd(&stats[(NGRAPH + g) * HC + f], ss);
}

__global__ void gn_finalize_kernel(const float* __restrict__ stats, const int* __restrict__ cntInt,
                                   const float* __restrict__ gnw, const float* __restrict__ gnb,
                                   const float* __restrict__ gnms, int row,
                                   float* __restrict__ scsh) {
  int i = blockIdx.x * 256 + threadIdx.x;
  if (i >= NGRAPH * HC) return;
  int g = i / HC, f = i - g * HC;
  float c = fmaxf((float)cntInt[g], 1.0f);
  float m = stats[i] / c;
  float sq = stats[NGRAPH * HC + i] / c;
  float ms = gnms[row * HC + f];
  float var = sq - m * m * ms * (2.0f - ms);
  float w = gnw[row * HC + f], b = gnb[row * HC + f];
  float scale = w / sqrtf(var + 1e-5f);
  float shift = b - scale * ms * m;
  scsh[i] = scale;
  scsh[NGRAPH * HC + i] = shift;
}

// =====================================================================
// Per-graph counts + start offsets via binary search (batch sorted).
// =====================================================================
__global__ void cnt_bsearch_kernel(const int* __restrict__ batch, int* __restrict__ cntInt,
                                   int* __restrict__ gstart) {
  int g = threadIdx.x;
  if (g >= NGRAPH) return;
  auto lb = [&](int v) {
    int lo = 0, hi = N_NODES;
    while (lo < hi) {
      int mid = (lo + hi) >> 1;
      if (batch[mid] < v) lo = mid + 1; else hi = mid;
    }
    return lo;
  };
  int a = lb(g), b = lb(g + 1);
  cntInt[g] = b - a;
  gstart[g] = a;
  if (g == NGRAPH - 1) gstart[NGRAPH] = N_NODES;
}

// =====================================================================
// CSR build by destination
// =====================================================================
__global__ void deg_hist_kernel(const int* __restrict__ dstE, int* __restrict__ deg) {
  int e = blockIdx.x * 256 + threadIdx.x;
  if (e < N_EDGES) atomicAdd(&deg[dstE[e]], 1);
}

__global__ void scan1_kernel(const int* __restrict__ deg, int* __restrict__ bsum) {
  __shared__ int sd[256];
  int i = blockIdx.x * 256 + threadIdx.x;
  sd[threadIdx.x] = (i < N_NODES) ? deg[i] : 0;
  __syncthreads();
  for (int s = 128; s > 0; s >>= 1) {
    if (threadIdx.x < s) sd[threadIdx.x] += sd[threadIdx.x + s];
    __syncthreads();
  }
  if (threadIdx.x == 0) bsum[blockIdx.x] = sd[0];
}

__global__ void scan2_kernel(int* __restrict__ bsum, int nb) {
  __shared__ int sd[256];
  int t = threadIdx.x;
  int v0 = (t < nb) ? bsum[t] : 0;
  sd[t] = v0;
  __syncthreads();
  for (int s = 1; s < 256; s <<= 1) {
    int v = (t >= s) ? sd[t - s] : 0;
    __syncthreads();
    sd[t] += v;
    __syncthreads();
  }
  if (t < nb) bsum[t] = sd[t] - v0;  // exclusive
}

__global__ void scan3_kernel(const int* __restrict__ deg, const int* __restrict__ bsum,
                             int* __restrict__ rowptr) {
  __shared__ int sd[256];
  int i = blockIdx.x * 256 + threadIdx.x;
  int t = threadIdx.x;
  int d = (i < N_NODES) ? deg[i] : 0;
  sd[t] = d;
  __syncthreads();
  for (int s = 1; s < 256; s <<= 1) {
    int v = (t >= s) ? sd[t - s] : 0;
    __syncthreads();
    sd[t] += v;
    __syncthreads();
  }
  if (i < N_NODES) rowptr[i] = bsum[blockIdx.x] + sd[t] - d;
  if (i == 0) rowptr[N_NODES] = N_EDGES;
}

__global__ void scatter_kernel(const int* __restrict__ srcE, const int* __restrict__ dstE,
                               const int* __restrict__ rowptr, int* __restrict__ fill,
                               int* __restrict__ colA) {
  int e = blockIdx.x * 256 + threadIdx.x;
  if (e < N_EDGES) {
    int d = dstE[e];
    int pos = rowptr[d] + atomicAdd(&fill[d], 1);
    colA[pos] = srcE[e];
  }
}

// =====================================================================
// GATv2 attention (R9 main body) + GraphNorm stats fused via per-block
// PARTIAL ARRAYS (non-atomic coalesced stores); only graph-straddling
// nodes use atomics.
// =====================================================================
#define AEDGE(V, D, ACC)                                                      \
  do {                                                                        \
    float e0 = (V).x + xrv.x; e0 = fmaxf(e0, 0.2f * e0);                      \
    float e1 = (V).y + xrv.y; e1 = fmaxf(e1, 0.2f * e1);                      \
    float e2 = (V).z + xrv.z; e2 = fmaxf(e2, 0.2f * e2);                      \
    float e3 = (V).w + xrv.w; e3 = fmaxf(e3, 0.2f * e3);                      \
    float p = fmaf(e3, av.w, fmaf(e2, av.z, fmaf(e1, av.y, e0 * av.x)));      \
    p += __shfl_xor(p, 1);                                                    \
    p += __shfl_xor(p, 2);                                                    \
    float pp = __expf(p);                                                     \
    (D) += pp;                                                                \
    (ACC).x = fmaf(pp, (V).x, (ACC).x);                                       \
    (ACC).y = fmaf(pp, (V).y, (ACC).y);                                       \
    (ACC).z = fmaf(pp, (V).z, (ACC).z);                                       \
    (ACC).w = fmaf(pp, (V).w, (ACC).w);                                       \
  } while (0)

__global__ __launch_bounds__(256) void attn_concat_kernel(
    const float* __restrict__ xl, const float* __restrict__ xr,
    const float* __restrict__ att, const int* __restrict__ rowptr,
    const int* __restrict__ colA, float* __restrict__ out,
    const int* __restrict__ batch, float* __restrict__ stats,
    float* __restrict__ parts, float* __restrict__ partq) {
  __shared__ float sv[4 * HC];
  int t = threadIdx.x;
  int node = blockIdx.x * 4 + (t >> 6);
  int lane = t & 63;
  if (lane < 44) {  // node < N always (grid = N/4 exactly)
    const float4 av = *(const float4*)(att + lane * 4);
    size_t base = (size_t)node * HC + lane * 4;
    const float4 xrv = *(const float4*)(xr + base);
    int start = rowptr[node], end = rowptr[node + 1];
    float d = 0.0f, dB = 0.0f;
    float4 acc = make_float4(0.f, 0.f, 0.f, 0.f);
    float4 accB = make_float4(0.f, 0.f, 0.f, 0.f);
    float4 p1, p2;
    if (start < end)     p1 = *(const float4*)(xl + (size_t)colA[start] * HC + lane * 4);
    if (start + 1 < end) p2 = *(const float4*)(xl + (size_t)colA[start + 1] * HC + lane * 4);
    {
      float4 svv = *(const float4*)(xl + base);  // self-loop
      AEDGE(svv, d, acc);
    }
    int j = start;
    for (; j + 3 < end; j += 2) {
      float4 n1 = *(const float4*)(xl + (size_t)colA[j + 2] * HC + lane * 4);
      float4 n2 = *(const float4*)(xl + (size_t)colA[j + 3] * HC + lane * 4);
      AEDGE(p1, d, acc);
      AEDGE(p2, dB, accB);
      p1 = n1; p2 = n2;
    }
    if (j < end)     AEDGE(p1, d, acc);
    if (j + 1 < end) AEDGE(p2, dB, accB);
    if (j + 2 < end) {
      float4 n1 = *(const float4*)(xl + (size_t)colA[j + 2] * HC + lane * 4);
      AEDGE(n1, d, acc);
    }
    d += dB;
    acc.x += accB.x; acc.y += accB.y; acc.z += accB.z; acc.w += accB.w;
    float rd = 1.0f / (d + 1e-16f);
    float4 o = *(const float4*)(out + base);  // residual+bias already there
    o.x = fmaf(acc.x, rd, o.x);
    o.y = fmaf(acc.y, rd, o.y);
    o.z = fmaf(acc.z, rd, o.z);
    o.w = fmaf(acc.w, rd, o.w);
    *(float4*)(out + base) = o;
    *(float4*)(&sv[(t >> 6) * HC + lane * 4]) = o;
  }
  __syncthreads();
  if (t < HC) {
    int b = blockIdx.x;
    int g0 = batch[b * 4];
    float s = 0.0f, ss = 0.0f;
#pragma unroll
    for (int w = 0; w < 4; w++) {
      int g = batch[b * 4 + w];
      float v = sv[w * HC + t];
      if (g == g0) {
        s += v;
        ss = fmaf(v, v, ss);
      } else {  // rare graph-straddle: direct atomic
        atomicAdd(&stats[g * HC + t], v);
        atomicAdd(&stats[(NGRAPH + g) * HC + t], v * v);
      }
    }
    parts[(size_t)b * HC + t] = s;
    partq[(size_t)b * HC + t] = ss;
  }
}

__global__ __launch_bounds__(256) void attn_mean_kernel(
    const float* __restrict__ xl, const float* __restrict__ xr,
    const float* __restrict__ att, const int* __restrict__ rowptr,
    const int* __restrict__ colA, const float* __restrict__ res16,
    float* __restrict__ out16) {
  int t = threadIdx.x;
  int node = blockIdx.x * 4 + (t >> 6);
  int lane = t & 63;
  if (node >= N_NODES) return;
  int L = (lane < 44) ? lane : 0;  // lanes 44..63 ride along (zeroed later)
  const float4 av = *(const float4*)(att + L * 4);
  size_t base = (size_t)node * HC + L * 4;
  const float4 xrv = *(const float4*)(xr + base);
  int start = rowptr[node], end = rowptr[node + 1];
  float d = 0.0f, dB = 0.0f;
  float4 acc = make_float4(0.f, 0.f, 0.f, 0.f);
  float4 accB = make_float4(0.f, 0.f, 0.f, 0.f);
  float4 p1, p2;
  if (start < end)     p1 = *(const float4*)(xl + (size_t)colA[start] * HC + L * 4);
  if (start + 1 < end) p2 = *(const float4*)(xl + (size_t)colA[start + 1] * HC + L * 4);
  {
    float4 sv = *(const float4*)(xl + base);
    AEDGE(sv, d, acc);
  }
  int j = start;
  for (; j + 3 < end; j += 2) {
    float4 n1 = *(const float4*)(xl + (size_t)colA[j + 2] * HC + L * 4);
    float4 n2 = *(const float4*)(xl + (size_t)colA[j + 3] * HC + L * 4);
    AEDGE(p1, d, acc);
    AEDGE(p2, dB, accB);
    p1 = n1; p2 = n2;
  }
  if (j < end)     AEDGE(p1, d, acc);
  if (j + 1 < end) AEDGE(p2, dB, accB);
  if (j + 2 < end) {
    float4 n1 = *(const float4*)(xl + (size_t)colA[j + 2] * HC + L * 4);
    AEDGE(n1, d, acc);
  }
  d += dB;
  acc.x += accB.x; acc.y += accB.y; acc.z += accB.z; acc.w += accB.w;
  float rd = 1.0f / (d + 1e-16f);
  float4 o;
  o.x = (lane < 44) ? acc.x * rd : 0.0f;
  o.y = (lane < 44) ? acc.y * rd : 0.0f;
  o.z = (lane < 44) ? acc.z * rd : 0.0f;
  o.w = (lane < 44) ? acc.w * rd : 0.0f;
#pragma unroll
  for (int w = 4; w <= 32; w <<= 1) {
    o.x += __shfl_xor(o.x, w);
    o.y += __shfl_xor(o.y, w);
    o.z += __shfl_xor(o.z, w);
    o.w += __shfl_xor(o.w, w);
  }
  if (lane < 4) {
    const float* rp = res16 + (size_t)node * 16 + lane * 4;
    float4 r = *(const float4*)rp;
    float4 ov;
    ov.x = fmaxf(fmaf(o.x, 1.0f / 11.0f, r.x), 0.0f);
    ov.y = fmaxf(fmaf(o.y, 1.0f / 11.0f, r.y), 0.0f);
    ov.z = fmaxf(fmaf(o.z, 1.0f / 11.0f, r.z), 0.0f);
    ov.w = fmaxf(fmaf(o.w, 1.0f / 11.0f, r.w), 0.0f);
    *(float4*)(out16 + (size_t)node * 16 + lane * 4) = ov;
  }
}

// =====================================================================
// res16 = normApply(h) @ c5_Wres(176x16) + c5_b   (norm+relu fused in load)
// =====================================================================
__global__ __launch_bounds__(256) void res16_kernel(const float* __restrict__ h,
                                                    const float* __restrict__ scsh,
                                                    const int* __restrict__ batch,
                                                    const float* __restrict__ Wres,
                                                    const float* __restrict__ b16,
                                                    float* __restrict__ res16) {
  __shared__ float Ws[176 * 16];
  __shared__ float hs[16 * 176];
  int t = threadIdx.x;
  for (int i = t; i < 176 * 16; i += 256) Ws[i] = Wres[i];
  int n0 = blockIdx.x * 16;
  for (int i = t; i < 16 * 176; i += 256) {
    int row = i / 176, k = i - row * 176;
    int g = batch[n0 + row];
    float v = h[(size_t)n0 * HC + i];
    hs[i] = fmaxf(fmaf(v, scsh[g * HC + k], scsh[(NGRAPH + g) * HC + k]), 0.0f);
  }
  __syncthreads();
  int tx = t & 15, ty = t >> 4;
  float acc = b16[tx];
  for (int k = 0; k < HC; k++) acc = fmaf(hs[ty * HC + k], Ws[k * 16 + tx], acc);
  res16[(size_t)(n0 + ty) * 16 + tx] = acc;
}

// =====================================================================
// Head MLP
// =====================================================================
__global__ __launch_bounds__(256) void head_kernel(
    const float* __restrict__ in16, const float* __restrict__ Wo1,
    const float* __restrict__ bo1, const float* __restrict__ Wo2,
    const float* __restrict__ bo2, const float* __restrict__ Wc,
    const float* __restrict__ bc, float* __restrict__ outp) {
  __shared__ float w1[256], w2[512], wcS[320], b1[16], b2[32], bcS[10];
  int t = threadIdx.x;
  for (int i = t; i < 256; i += 256) w1[i] = Wo1[i];
  for (int i = t; i < 512; i += 256) w2[i] = Wo2[i];
  for (int i = t; i < 320; i += 256) wcS[i] = Wc[i];
  if (t < 16) b1[t] = bo1[t];
  if (t < 32) b2[t] = bo2[t];
  if (t < 10) bcS[t] = bc[t];
  __syncthreads();
  int n = blockIdx.x * 256 + t;
  if (n >= N_NODES) return;
  float x[16];
#pragma unroll
  for (int i = 0; i < 16; i++) x[i] = in16[(size_t)n * 16 + i];
  float o1[16];
#pragma unroll
  for (int j = 0; j < 16; j++) {
    float a = b1[j];
#pragma unroll
    for (int k = 0; k < 16; k++) a = fmaf(x[k], w1[k * 16 + j], a);
    o1[j] = fmaxf(a, 0.0f);
  }
  float o2[32];
#pragma unroll
  for (int j = 0; j < 32; j++) {
    float a = b2[j];
#pragma unroll
    for (int k = 0; k < 16; k++) a = fmaf(o1[k], w2[k * 32 + j], a);
    o2[j] = fmaxf(a, 0.0f);
  }
#pragma unroll
  for (int j = 0; j < 10; j++) {
    float a = bcS[j];
#pragma unroll
    for (int k = 0; k < 32; k++) a = fmaf(o2[k], wcS[k * 10 + j], a);
    outp[(size_t)n * 10 + j] = a;
  }
}

// =====================================================================
extern "C" void kernel_launch(void* const* d_in, const int* in_sizes, int n_in,
                              void* d_out, int out_size, void* d_ws, size_t ws_size,
                              hipStream_t stream) {
  (void)in_sizes; (void)n_in; (void)out_size; (void)ws_size;
  const float* x     = (const float*)d_in[0];
  const int*   ei    = (const int*)d_in[1];
  const int*   srcE  = ei;
  const int*   dstE  = ei + N_EDGES;
  const int*   batch = (const int*)d_in[2];
  const float* W_pre = (const float*)d_in[3];
  const float* b_pre = (const float*)d_in[4];
  const float* gn_w  = (const float*)d_in[5];
  const float* gn_b  = (const float*)d_in[6];
  const float* gn_ms = (const float*)d_in[7];
  const float* cWl   = (const float*)d_in[8];
  const float* cWr   = (const float*)d_in[9];
  const float* cAtt  = (const float*)d_in[10];
  const float* cB    = (const float*)d_in[11];
  const float* cWres = (const float*)d_in[12];
  const float* c5Wl  = (const float*)d_in[13];
  const float* c5Wr  = (const float*)d_in[14];
  const float* c5Att = (const float*)d_in[15];
  const float* c5b   = (const float*)d_in[16];
  const float* c5Wres= (const float*)d_in[17];
  const float* Wo1   = (const float*)d_in[18];
  const float* bo1   = (const float*)d_in[19];
  const float* Wo2   = (const float*)d_in[20];
  const float* bo2   = (const float*)d_in[21];
  const float* Wc    = (const float*)d_in[22];
  const float* bc    = (const float*)d_in[23];

  const size_t FB = (size_t)N_NODES * HC;
  const size_t STB = (size_t)2 * NGRAPH * HC;  // one stats buffer (22528 floats)
  const size_t PB = (size_t)NBLK_ATTN * HC;    // 2.2M floats per partial array
  float* ws    = (float*)d_ws;
  float* buf0  = ws;
  float* buf1  = ws + FB;
  float* buf2  = ws + 2 * FB;
  float* buf3  = ws + 3 * FB;
  float* res16 = ws + 4 * FB;
  float* out16 = res16 + (size_t)N_NODES * 16;
  float* stats = out16 + (size_t)N_NODES * 16;         // 5 buffers
  float* scsh  = stats + 5 * STB;
  float* parts = scsh + STB;
  float* partq = parts + PB;
  _Float16* wph = (_Float16*)(partq + PB);             // 991232 halves
  int* ibase   = (int*)((char*)wph + (size_t)991232 * 2);
  int* cntInt  = ibase;
  int* gstart  = ibase + 64;                           // 65 ints
  int* deg     = gstart + 65;
  int* fill    = deg + N_NODES;
  int* rowptr  = fill + N_NODES;
  int* colA    = rowptr + N_NODES + 1;
  int* bsum    = colA + N_EDGES;

  const int NB = (N_NODES + 255) / 256;

  hipMemsetAsync(deg, 0, sizeof(int) * 2 * N_NODES, stream);
  hipMemsetAsync(stats, 0, sizeof(float) * 5 * STB, stream);  // all layers at once

  prep_kernel<<<(TOT_PAIRS + 255) / 256, 256, 0, stream>>>(W_pre, cWl, cWr, cWres, c5Wl, c5Wr, wph);
  cnt_bsearch_kernel<<<1, 64, 0, stream>>>(batch, cntInt, gstart);
  deg_hist_kernel<<<(N_EDGES + 255) / 256, 256, 0, stream>>>(dstE, deg);
  scan1_kernel<<<NB, 256, 0, stream>>>(deg, bsum);
  scan2_kernel<<<1, 256, 0, stream>>>(bsum, NB);
  scan3_kernel<<<NB, 256, 0, stream>>>(deg, bsum, rowptr);
  scatter_kernel<<<(N_EDGES + 255) / 256, 256, 0, stream>>>(srcE, dstE, rowptr, fill, colA);

  const int GNB = (N_NODES + 63) / 64;  // 782 blocks for layer-0 gn_stats
  const int PRB = (NGRAPH * NCHUNK * HC + 255) / 256;  // 704 blocks for part_reduce

  // pre: buf0 = x @ W_pre + b_pre  (raw, no norm on input)
  gemm_mfma<<<GX8 * 1 * 8, 256, 0, stream>>>(x, N_NODES, IN_F, 4, 1, wph, 0,
                                             nullptr, nullptr,
                                             b_pre, nullptr, nullptr,
                                             buf0, nullptr, nullptr);
  gn_stats_kernel<<<GNB, 256, 0, stream>>>(buf0, batch, stats);
  gn_finalize_kernel<<<(NGRAPH * HC + 255) / 256, 256, 0, stream>>>(stats, cntInt, gn_w, gn_b, gn_ms, 0, scsh);

  float* h = buf0;  // raw buffer; norm applied on the fly by consumers
  float* o = buf3;
  for (int i = 0; i < 4; i++) {
    const _Float16* Wcat_i = wph + PREH + (size_t)(3 * i) * MATH;
    gemm_mfma<<<GX8 * 3 * 8, 256, 0, stream>>>(h, N_NODES, HC, 6, 3, Wcat_i, MATH,
                                               scsh, batch,
                                               nullptr, nullptr, cB + i * HC,
                                               buf1, buf2, o);
    float* st = stats + (size_t)(i + 1) * STB;
    attn_concat_kernel<<<NBLK_ATTN, 256, 0, stream>>>(buf1, buf2, cAtt + i * HC,
                                                      rowptr, colA, o, batch, st,
                                                      parts, partq);
    part_reduce_kernel<<<PRB, 256, 0, stream>>>(parts, partq, gstart, st);
    gn_finalize_kernel<<<(NGRAPH * HC + 255) / 256, 256, 0, stream>>>(st, cntInt, gn_w, gn_b, gn_ms, i + 1, scsh);
    float* tmp = h; h = o; o = tmp;
  }

  // conv5 (input = raw h with scsh row 4 fused in consumers)
  const _Float16* Wc5 = wph + PREH + (size_t)12 * MATH;
  gemm_mfma<<<GX8 * 2 * 8, 256, 0, stream>>>(h, N_NODES, HC, 6, 2, Wc5, MATH,
                                             scsh, batch,
                                             nullptr, nullptr, nullptr,
                                             buf1, buf2, nullptr);
  res16_kernel<<<N_NODES / 16, 256, 0, stream>>>(h, scsh, batch, c5Wres, c5b, res16);
  attn_mean_kernel<<<(N_NODES + 3) / 4, 256, 0, stream>>>(buf1, buf2, c5Att, rowptr, colA, res16, out16);

  head_kernel<<<NB, 256, 0, stream>>>(out16, Wo1, bo1, Wo2, bo2, Wc, bc, (float*)d_out);
}

// Round 16
// 763.968 us; speedup vs baseline: 1.1235x; 1.0448x over previous
//
#include <hip/hip_runtime.h>
#include <math.h>

#define N_NODES 50000
#define N_EDGES 400000
#define IN_F 128
#define HC 176
#define NGRAPH 64
#define NBLK_ATTN 12500   // N_NODES/4 exactly
#define NCHUNK 16         // part_reduce chunks per graph

typedef _Float16 half8 __attribute__((ext_vector_type(8)));
typedef float floatx4 __attribute__((ext_vector_type(4)));

// =====================================================================
// Packed split-fp16 weights in MFMA B-fragment order.
// =====================================================================
#define PREH 45056   // 4*11*2*512 halves
#define MATH 67584   // 6*11*2*512 halves
#define TOT_PAIRS 495616  // 22528 + 14*33792
#define KCBYTES 22528     // bytes per kc chunk (11*2*512*2)
#define GX8 49            // row-tile groups of 8 (49*8=392 >= 391 tiles)

__global__ void prep_kernel(const float* __restrict__ Wpre,
                            const float* __restrict__ cWl, const float* __restrict__ cWr,
                            const float* __restrict__ cWres,
                            const float* __restrict__ c5Wl, const float* __restrict__ c5Wr,
                            _Float16* __restrict__ wp) {
  int gid = blockIdx.x * 256 + threadIdx.x;
  if (gid >= TOT_PAIRS) return;
  int mat, idx;
  if (gid < 22528) { mat = 0; idx = gid; }
  else { int g = gid - 22528; mat = 1 + g / 33792; idx = g % 33792; }
  int kc = idx / 5632;
  int rem = idx - kc * 5632;
  int ct = rem / 512;
  int li = rem - ct * 512;
  int lane = li >> 3, j = li & 7;
  int k = kc * 32 + ((lane >> 4) << 3) + j;
  int col = ct * 16 + (lane & 15);
  const float* src; int Ksrc; size_t base;
  if (mat == 0) { src = Wpre; Ksrc = 128; base = 0; }
  else if (mat <= 12) {
    int lm = mat - 1; int layer = lm / 3; int sub = lm - layer * 3;
    const float* s = (sub == 0) ? cWl : (sub == 1) ? cWr : cWres;
    src = s + (size_t)layer * HC * HC; Ksrc = HC;
    base = PREH + (size_t)lm * MATH;
  } else {
    src = (mat == 13) ? c5Wl : c5Wr; Ksrc = HC;
    base = PREH + (size_t)12 * MATH + (size_t)(mat - 13) * MATH;
  }
  float v = (k < Ksrc) ? src[(size_t)k * HC + col] : 0.0f;
  _Float16 h = (_Float16)v;
  _Float16 l = (_Float16)(v - (float)h);
  size_t o = base + (size_t)(kc * 11 + ct) * 1024 + li;
  wp[o] = h;
  wp[o + 512] = l;
}

// =====================================================================
// Split-fp16 MFMA GEMM with block-level LDS staging of B (R7) + XCD
// swizzle (R8). MINW: min waves/EU (3 -> 3 blocks/CU for conv; LDS
// 45KB*3=135<=160KB). DOSTATS: fused per-tile GraphNorm partials in the
// epilogue (pre-GEMM only; staging LDS reused for the reduction).
// grid.x = GX8 * nmat * 8.
// =====================================================================
template <int MINW, bool DOSTATS>
__global__ __launch_bounds__(256, MINW) void gemm_mfma_t(
    const float* __restrict__ A, int M, int K, int nkc, int nmat,
    const _Float16* __restrict__ Wp, int matStride,
    const float* __restrict__ scsh, const int* __restrict__ batch,
    const float* __restrict__ bias0, const float* __restrict__ bias1,
    const float* __restrict__ bias2,
    float* __restrict__ out0, float* __restrict__ out1, float* __restrict__ out2,
    float* __restrict__ parts, float* __restrict__ partq, float* __restrict__ stats) {
  __shared__ __align__(16) char smem[2 * KCBYTES];
  const int b = blockIdx.x;
  const int grp = b >> 3, sub = b & 7;
  const int mat = grp % nmat;
  const int tile = ((grp / nmat) << 3) | sub;
  if (tile * 128 >= M) return;
  const _Float16* W = Wp + (size_t)mat * matStride;
  float* outp = (mat == 0) ? out0 : (mat == 1) ? out1 : out2;
  const float* bias = (mat == 0) ? bias0 : (mat == 1) ? bias1 : bias2;
  const int tid = threadIdx.x;
  const int lane = tid & 63;
  const int wv = tid >> 6;
  const int m16 = lane & 15, quad = lane >> 4;
  const int kb = quad << 3;
  const int rowBase = tile * 128 + wv * 32;
  const int rA0 = min(rowBase + m16, M - 1);
  const int rA1 = min(rowBase + 16 + m16, M - 1);
  const float* ap0 = A + (size_t)rA0 * K + kb;
  const float* ap1 = A + (size_t)rA1 * K + kb;
  const float* sc0 = nullptr; const float* sh0 = nullptr;
  const float* sc1 = nullptr; const float* sh1 = nullptr;
  if (scsh) {
    int g0 = batch[rA0], g1 = batch[rA1];
    sc0 = scsh + (size_t)g0 * HC + kb;
    sh0 = scsh + (size_t)(NGRAPH + g0) * HC + kb;
    sc1 = scsh + (size_t)g1 * HC + kb;
    sh1 = scsh + (size_t)(NGRAPH + g1) * HC + kb;
  }

  auto stage = [&](int kc, int buf) {
    const char* src = (const char*)W + (size_t)kc * KCBYTES;
    char* dst = smem + buf * KCBYTES;
#pragma unroll
    for (int i = 0; i < 6; i++) {
      int idx = wv * 6 + i;
      if (idx < 22) {
        __builtin_amdgcn_global_load_lds(
            (const __attribute__((address_space(1))) unsigned int*)(src + idx * 1024 + lane * 16),
            (__attribute__((address_space(3))) unsigned int*)(dst + idx * 1024),
            16, 0, 0);
      }
    }
  };

  floatx4 acc0[11], acc1[11];
#pragma unroll
  for (int ct = 0; ct < 11; ct++)
#pragma unroll
    for (int r = 0; r < 4; r++) { acc0[ct][r] = 0.0f; acc1[ct][r] = 0.0f; }

  stage(0, 0);

  for (int kc = 0; kc < nkc; kc++) {
    const int buf = kc & 1;
    __syncthreads();
    if (kc + 1 < nkc) stage(kc + 1, 1 - buf);

    const int koff = kc << 5;
    float va0[8], va1[8];
    if (koff + kb + 8 <= K) {
      float4 u0 = *(const float4*)(ap0 + koff);
      float4 u1 = *(const float4*)(ap0 + koff + 4);
      float4 w0 = *(const float4*)(ap1 + koff);
      float4 w1 = *(const float4*)(ap1 + koff + 4);
      va0[0] = u0.x; va0[1] = u0.y; va0[2] = u0.z; va0[3] = u0.w;
      va0[4] = u1.x; va0[5] = u1.y; va0[6] = u1.z; va0[7] = u1.w;
      va1[0] = w0.x; va1[1] = w0.y; va1[2] = w0.z; va1[3] = w0.w;
      va1[4] = w1.x; va1[5] = w1.y; va1[6] = w1.z; va1[7] = w1.w;
      if (scsh) {
        float s0[8], h0[8], s1[8], h1[8];
        float4 t;
        t = *(const float4*)(sc0 + koff);     s0[0]=t.x; s0[1]=t.y; s0[2]=t.z; s0[3]=t.w;
        t = *(const float4*)(sc0 + koff + 4); s0[4]=t.x; s0[5]=t.y; s0[6]=t.z; s0[7]=t.w;
        t = *(const float4*)(sh0 + koff);     h0[0]=t.x; h0[1]=t.y; h0[2]=t.z; h0[3]=t.w;
        t = *(const float4*)(sh0 + koff + 4); h0[4]=t.x; h0[5]=t.y; h0[6]=t.z; h0[7]=t.w;
        t = *(const float4*)(sc1 + koff);     s1[0]=t.x; s1[1]=t.y; s1[2]=t.z; s1[3]=t.w;
        t = *(const float4*)(sc1 + koff + 4); s1[4]=t.x; s1[5]=t.y; s1[6]=t.z; s1[7]=t.w;
        t = *(const float4*)(sh1 + koff);     h1[0]=t.x; h1[1]=t.y; h1[2]=t.z; h1[3]=t.w;
        t = *(const float4*)(sh1 + koff + 4); h1[4]=t.x; h1[5]=t.y; h1[6]=t.z; h1[7]=t.w;
#pragma unroll
        for (int j = 0; j < 8; j++) {
          va0[j] = fmaxf(fmaf(va0[j], s0[j], h0[j]), 0.0f);
          va1[j] = fmaxf(fmaf(va1[j], s1[j], h1[j]), 0.0f);
        }
      }
    } else {
#pragma unroll
      for (int j = 0; j < 8; j++) { va0[j] = 0.0f; va1[j] = 0.0f; }
    }
    half8 ah0, al0, ah1, al1;
#pragma unroll
    for (int j = 0; j < 8; j++) {
      _Float16 h = (_Float16)va0[j];
      ah0[j] = h; al0[j] = (_Float16)(va0[j] - (float)h);
      _Float16 g = (_Float16)va1[j];
      ah1[j] = g; al1[j] = (_Float16)(va1[j] - (float)g);
    }
    const char* bbase = smem + buf * KCBYTES + lane * 16;
#pragma unroll
    for (int ct = 0; ct < 11; ct++) {
      half8 bh = *(const half8*)(bbase + ct * 2048);
      half8 bl = *(const half8*)(bbase + ct * 2048 + 1024);
      acc0[ct] = __builtin_amdgcn_mfma_f32_16x16x32_f16(ah0, bh, acc0[ct], 0, 0, 0);
      acc1[ct] = __builtin_amdgcn_mfma_f32_16x16x32_f16(ah1, bh, acc1[ct], 0, 0, 0);
      acc0[ct] = __builtin_amdgcn_mfma_f32_16x16x32_f16(al0, bh, acc0[ct], 0, 0, 0);
      acc1[ct] = __builtin_amdgcn_mfma_f32_16x16x32_f16(al1, bh, acc1[ct], 0, 0, 0);
      acc0[ct] = __builtin_amdgcn_mfma_f32_16x16x32_f16(ah0, bl, acc0[ct], 0, 0, 0);
      acc1[ct] = __builtin_amdgcn_mfma_f32_16x16x32_f16(ah1, bl, acc1[ct], 0, 0, 0);
    }
  }

  float bv[11];
#pragma unroll
  for (int ct = 0; ct < 11; ct++) bv[ct] = bias ? bias[ct * 16 + m16] : 0.0f;
#pragma unroll
  for (int r = 0; r < 4; r++) {
    int row0 = rowBase + (quad << 2) + r;
    if (row0 < M) {
      float* op = outp + (size_t)row0 * HC + m16;
#pragma unroll
      for (int ct = 0; ct < 11; ct++) op[ct * 16] = acc0[ct][r] + bv[ct];
    }
    int row1 = row0 + 16;
    if (row1 < M) {
      float* op = outp + (size_t)row1 * HC + m16;
#pragma unroll
      for (int ct = 0; ct < 11; ct++) op[ct * 16] = acc1[ct][r] + bv[ct];
    }
  }

  if (DOSTATS) {
    // ---- fused GraphNorm per-tile partials (128 rows, <=2 graphs) ----
    int gTile = batch[tile * 128];  // tile*128 < M guaranteed
    int lastRow = min(tile * 128 + 127, M - 1);
    bool straddle = (batch[lastRow] != gTile);
    bool validR[8]; bool otherR[8];
#pragma unroll
    for (int r = 0; r < 4; r++) {
      int row0 = rowBase + (quad << 2) + r;
      validR[r] = (row0 < M);
      otherR[r] = validR[r] && (batch[min(row0, M - 1)] != gTile);
      int row1 = row0 + 16;
      validR[4 + r] = (row1 < M);
      otherR[4 + r] = validR[4 + r] && (batch[min(row1, M - 1)] != gTile);
    }
    __syncthreads();  // staging LDS no longer needed; reuse for reduction
    float* red = (float*)smem;  // [4][11][16][4]
#pragma unroll
    for (int ct = 0; ct < 11; ct++) {
      float sA = 0.f, qA = 0.f, sB = 0.f, qB = 0.f;
#pragma unroll
      for (int r = 0; r < 4; r++) {
        if (validR[r]) {
          float v = acc0[ct][r] + bv[ct];
          if (otherR[r]) { sB += v; qB = fmaf(v, v, qB); }
          else           { sA += v; qA = fmaf(v, v, qA); }
        }
        if (validR[4 + r]) {
          float v = acc1[ct][r] + bv[ct];
          if (otherR[4 + r]) { sB += v; qB = fmaf(v, v, qB); }
          else               { sA += v; qA = fmaf(v, v, qA); }
        }
      }
      sA += __shfl_xor(sA, 16); sA += __shfl_xor(sA, 32);
      qA += __shfl_xor(qA, 16); qA += __shfl_xor(qA, 32);
      sB += __shfl_xor(sB, 16); sB += __shfl_xor(sB, 32);
      qB += __shfl_xor(qB, 16); qB += __shfl_xor(qB, 32);
      if (quad == 0) {
        float* slot = red + (((wv * 11 + ct) * 16 + m16) << 2);
        slot[0] = sA; slot[1] = qA; slot[2] = sB; slot[3] = qB;
      }
    }
    __syncthreads();
    if (tid < HC) {
      int col = tid;
      float sA = 0.f, qA = 0.f, sB = 0.f, qB = 0.f;
#pragma unroll
      for (int w = 0; w < 4; w++) {
        float* slot = red + (((w * 11 + col / 16) * 16 + (col & 15)) << 2);
        sA += slot[0]; qA += slot[1]; sB += slot[2]; qB += slot[3];
      }
      parts[(size_t)tile * HC + col] = sA;
      partq[(size_t)tile * HC + col] = qA;
      if (straddle) {
        int g2 = batch[lastRow];
        atomicAdd(&stats[g2 * HC + col], sB);
        atomicAdd(&stats[(NGRAPH + g2) * HC + col], qB);
      }
    }
  }
}

// =====================================================================
// Reduce per-block partials into stats. rpb = rows-per-partial-block
// (4 for attention partials, 128 for pre-GEMM tile partials).
// =====================================================================
__global__ __launch_bounds__(256) void part_reduce_kernel(
    const float* __restrict__ parts, const float* __restrict__ partq,
    const int* __restrict__ gstart, float* __restrict__ stats, int rpb) {
  int idx = blockIdx.x * 256 + threadIdx.x;
  if (idx >= NGRAPH * NCHUNK * HC) return;
  int f = idx % HC;
  int gc = idx / HC;
  int g = gc / NCHUNK, c = gc % NCHUNK;
  int s0 = gstart[g], s1 = gstart[g + 1];
  int b0 = (s0 + rpb - 1) / rpb, b1 = (s1 + rpb - 1) / rpb;
  int len = b1 - b0;
  if (len <= 0) return;
  int per = (len + NCHUNK - 1) / NCHUNK;
  int cb0 = b0 + c * per;
  int cb1 = min(cb0 + per, b1);
  if (cb0 >= cb1) return;
  float s = 0.f, ss = 0.f;
  for (int b = cb0; b < cb1; b++) {
    s += parts[(size_t)b * HC + f];
    ss += partq[(size_t)b * HC + f];
  }
  atomicAdd(&stats[g * HC + f], s);
  atomicAdd(&stats[(NGRAPH + g) * HC + f], ss);
}

__global__ void gn_finalize_kernel(const float* __restrict__ stats, const int* __restrict__ cntInt,
                                   const float* __restrict__ gnw, const float* __restrict__ gnb,
                                   const float* __restrict__ gnms, int row,
                                   float* __restrict__ scsh) {
  int i = blockIdx.x * 256 + threadIdx.x;
  if (i >= NGRAPH * HC) return;
  int g = i / HC, f = i - g * HC;
  float c = fmaxf((float)cntInt[g], 1.0f);
  float m = stats[i] / c;
  float sq = stats[NGRAPH * HC + i] / c;
  float ms = gnms[row * HC + f];
  float var = sq - m * m * ms * (2.0f - ms);
  float w = gnw[row * HC + f], b = gnb[row * HC + f];
  float scale = w / sqrtf(var + 1e-5f);
  float shift = b - scale * ms * m;
  scsh[i] = scale;
  scsh[NGRAPH * HC + i] = shift;
}

// =====================================================================
// Per-graph counts + start offsets via binary search (batch sorted).
// =====================================================================
__global__ void cnt_bsearch_kernel(const int* __restrict__ batch, int* __restrict__ cntInt,
                                   int* __restrict__ gstart) {
  int g = threadIdx.x;
  if (g >= NGRAPH) return;
  auto lb = [&](int v) {
    int lo = 0, hi = N_NODES;
    while (lo < hi) {
      int mid = (lo + hi) >> 1;
      if (batch[mid] < v) lo = mid + 1; else hi = mid;
    }
    return lo;
  };
  int a = lb(g), b = lb(g + 1);
  cntInt[g] = b - a;
  gstart[g] = a;
  if (g == NGRAPH - 1) gstart[NGRAPH] = N_NODES;
}

// =====================================================================
// CSR build by destination
// =====================================================================
__global__ void deg_hist_kernel(const int* __restrict__ dstE, int* __restrict__ deg) {
  int e = blockIdx.x * 256 + threadIdx.x;
  if (e < N_EDGES) atomicAdd(&deg[dstE[e]], 1);
}

__global__ void scan1_kernel(const int* __restrict__ deg, int* __restrict__ bsum) {
  __shared__ int sd[256];
  int i = blockIdx.x * 256 + threadIdx.x;
  sd[threadIdx.x] = (i < N_NODES) ? deg[i] : 0;
  __syncthreads();
  for (int s = 128; s > 0; s >>= 1) {
    if (threadIdx.x < s) sd[threadIdx.x] += sd[threadIdx.x + s];
    __syncthreads();
  }
  if (threadIdx.x == 0) bsum[blockIdx.x] = sd[0];
}

__global__ void scan2_kernel(int* __restrict__ bsum, int nb) {
  __shared__ int sd[256];
  int t = threadIdx.x;
  int v0 = (t < nb) ? bsum[t] : 0;
  sd[t] = v0;
  __syncthreads();
  for (int s = 1; s < 256; s <<= 1) {
    int v = (t >= s) ? sd[t - s] : 0;
    __syncthreads();
    sd[t] += v;
    __syncthreads();
  }
  if (t < nb) bsum[t] = sd[t] - v0;  // exclusive
}

__global__ void scan3_kernel(const int* __restrict__ deg, const int* __restrict__ bsum,
                             int* __restrict__ rowptr) {
  __shared__ int sd[256];
  int i = blockIdx.x * 256 + threadIdx.x;
  int t = threadIdx.x;
  int d = (i < N_NODES) ? deg[i] : 0;
  sd[t] = d;
  __syncthreads();
  for (int s = 1; s < 256; s <<= 1) {
    int v = (t >= s) ? sd[t - s] : 0;
    __syncthreads();
    sd[t] += v;
    __syncthreads();
  }
  if (i < N_NODES) rowptr[i] = bsum[blockIdx.x] + sd[t] - d;
  if (i == 0) rowptr[N_NODES] = N_EDGES;
}

__global__ void scatter_kernel(const int* __restrict__ srcE, const int* __restrict__ dstE,
                               const int* __restrict__ rowptr, int* __restrict__ fill,
                               int* __restrict__ colA) {
  int e = blockIdx.x * 256 + threadIdx.x;
  if (e < N_EDGES) {
    int d = dstE[e];
    int pos = rowptr[d] + atomicAdd(&fill[d], 1);
    colA[pos] = srcE[e];
  }
}

// =====================================================================
// GATv2 attention (R9 main body) + GraphNorm stats fused via per-block
// PARTIAL ARRAYS (non-atomic coalesced stores); only graph-straddling
// nodes use atomics.
// =====================================================================
#define AEDGE(V, D, ACC)                                                      \
  do {                                                                        \
    float e0 = (V).x + xrv.x; e0 = fmaxf(e0, 0.2f * e0);                      \
    float e1 = (V).y + xrv.y; e1 = fmaxf(e1, 0.2f * e1);                      \
    float e2 = (V).z + xrv.z; e2 = fmaxf(e2, 0.2f * e2);                      \
    float e3 = (V).w + xrv.w; e3 = fmaxf(e3, 0.2f * e3);                      \
    float p = fmaf(e3, av.w, fmaf(e2, av.z, fmaf(e1, av.y, e0 * av.x)));      \
    p += __shfl_xor(p, 1);                                                    \
    p += __shfl_xor(p, 2);                                                    \
    float pp = __expf(p);                                                     \
    (D) += pp;                                                                \
    (ACC).x = fmaf(pp, (V).x, (ACC).x);                                       \
    (ACC).y = fmaf(pp, (V).y, (ACC).y);                                       \
    (ACC).z = fmaf(pp, (V).z, (ACC).z);                                       \
    (ACC).w = fmaf(pp, (V).w, (ACC).w);                                       \
  } while (0)

__global__ __launch_bounds__(256) void attn_concat_kernel(
    const float* __restrict__ xl, const float* __restrict__ xr,
    const float* __restrict__ att, const int* __restrict__ rowptr,
    const int* __restrict__ colA, float* __restrict__ out,
    const int* __restrict__ batch, float* __restrict__ stats,
    float* __restrict__ parts, float* __restrict__ partq) {
  __shared__ float sv[4 * HC];
  int t = threadIdx.x;
  int node = blockIdx.x * 4 + (t >> 6);
  int lane = t & 63;
  if (lane < 44) {  // node < N always (grid = N/4 exactly)
    const float4 av = *(const float4*)(att + lane * 4);
    size_t base = (size_t)node * HC + lane * 4;
    const float4 xrv = *(const float4*)(xr + base);
    int start = rowptr[node], end = rowptr[node + 1];
    float d = 0.0f, dB = 0.0f;
    float4 acc = make_float4(0.f, 0.f, 0.f, 0.f);
    float4 accB = make_float4(0.f, 0.f, 0.f, 0.f);
    float4 p1, p2;
    if (start < end)     p1 = *(const float4*)(xl + (size_t)colA[start] * HC + lane * 4);
    if (start + 1 < end) p2 = *(const float4*)(xl + (size_t)colA[start + 1] * HC + lane * 4);
    {
      float4 svv = *(const float4*)(xl + base);  // self-loop
      AEDGE(svv, d, acc);
    }
    int j = start;
    for (; j + 3 < end; j += 2) {
      float4 n1 = *(const float4*)(xl + (size_t)colA[j + 2] * HC + lane * 4);
      float4 n2 = *(const float4*)(xl + (size_t)colA[j + 3] * HC + lane * 4);
      AEDGE(p1, d, acc);
      AEDGE(p2, dB, accB);
      p1 = n1; p2 = n2;
    }
    if (j < end)     AEDGE(p1, d, acc);
    if (j + 1 < end) AEDGE(p2, dB, accB);
    if (j + 2 < end) {
      float4 n1 = *(const float4*)(xl + (size_t)colA[j + 2] * HC + lane * 4);
      AEDGE(n1, d, acc);
    }
    d += dB;
    acc.x += accB.x; acc.y += accB.y; acc.z += accB.z; acc.w += accB.w;
    float rd = 1.0f / (d + 1e-16f);
    float4 o = *(const float4*)(out + base);  // residual+bias already there
    o.x = fmaf(acc.x, rd, o.x);
    o.y = fmaf(acc.y, rd, o.y);
    o.z = fmaf(acc.z, rd, o.z);
    o.w = fmaf(acc.w, rd, o.w);
    *(float4*)(out + base) = o;
    *(float4*)(&sv[(t >> 6) * HC + lane * 4]) = o;
  }
  __syncthreads();
  if (t < HC) {
    int b = blockIdx.x;
    int g0 = batch[b * 4];
    float s = 0.0f, ss = 0.0f;
#pragma unroll
    for (int w = 0; w < 4; w++) {
      int g = batch[b * 4 + w];
      float v = sv[w * HC + t];
      if (g == g0) {
        s += v;
        ss = fmaf(v, v, ss);
      } else {  // rare graph-straddle: direct atomic
        atomicAdd(&stats[g * HC + t], v);
        atomicAdd(&stats[(NGRAPH + g) * HC + t], v * v);
      }
    }
    parts[(size_t)b * HC + t] = s;
    partq[(size_t)b * HC + t] = ss;
  }
}

__global__ __launch_bounds__(256) void attn_mean_kernel(
    const float* __restrict__ xl, const float* __restrict__ xr,
    const float* __restrict__ att, const int* __restrict__ rowptr,
    const int* __restrict__ colA, const float* __restrict__ res16,
    float* __restrict__ out16) {
  int t = threadIdx.x;
  int node = blockIdx.x * 4 + (t >> 6);
  int lane = t & 63;
  if (node >= N_NODES) return;
  int L = (lane < 44) ? lane : 0;  // lanes 44..63 ride along (zeroed later)
  const float4 av = *(const float4*)(att + L * 4);
  size_t base = (size_t)node * HC + L * 4;
  const float4 xrv = *(const float4*)(xr + base);
  int start = rowptr[node], end = rowptr[node + 1];
  float d = 0.0f, dB = 0.0f;
  float4 acc = make_float4(0.f, 0.f, 0.f, 0.f);
  float4 accB = make_float4(0.f, 0.f, 0.f, 0.f);
  float4 p1, p2;
  if (start < end)     p1 = *(const float4*)(xl + (size_t)colA[start] * HC + L * 4);
  if (start + 1 < end) p2 = *(const float4*)(xl + (size_t)colA[start + 1] * HC + L * 4);
  {
    float4 sv = *(const float4*)(xl + base);
    AEDGE(sv, d, acc);
  }
  int j = start;
  for (; j + 3 < end; j += 2) {
    float4 n1 = *(const float4*)(xl + (size_t)colA[j + 2] * HC + L * 4);
    float4 n2 = *(const float4*)(xl + (size_t)colA[j + 3] * HC + L * 4);
    AEDGE(p1, d, acc);
    AEDGE(p2, dB, accB);
    p1 = n1; p2 = n2;
  }
  if (j < end)     AEDGE(p1, d, acc);
  if (j + 1 < end) AEDGE(p2, dB, accB);
  if (j + 2 < end) {
    float4 n1 = *(const float4*)(xl + (size_t)colA[j + 2] * HC + L * 4);
    AEDGE(n1, d, acc);
  }
  d += dB;
  acc.x += accB.x; acc.y += accB.y; acc.z += accB.z; acc.w += accB.w;
  float rd = 1.0f / (d + 1e-16f);
  float4 o;
  o.x = (lane < 44) ? acc.x * rd : 0.0f;
  o.y = (lane < 44) ? acc.y * rd : 0.0f;
  o.z = (lane < 44) ? acc.z * rd : 0.0f;
  o.w = (lane < 44) ? acc.w * rd : 0.0f;
#pragma unroll
  for (int w = 4; w <= 32; w <<= 1) {
    o.x += __shfl_xor(o.x, w);
    o.y += __shfl_xor(o.y, w);
    o.z += __shfl_xor(o.z, w);
    o.w += __shfl_xor(o.w, w);
  }
  if (lane < 4) {
    const float* rp = res16 + (size_t)node * 16 + lane * 4;
    float4 r = *(const float4*)rp;
    float4 ov;
    ov.x = fmaxf(fmaf(o.x, 1.0f / 11.0f, r.x), 0.0f);
    ov.y = fmaxf(fmaf(o.y, 1.0f / 11.0f, r.y), 0.0f);
    ov.z = fmaxf(fmaf(o.z, 1.0f / 11.0f, r.z), 0.0f);
    ov.w = fmaxf(fmaf(o.w, 1.0f / 11.0f, r.w), 0.0f);
    *(float4*)(out16 + (size_t)node * 16 + lane * 4) = ov;
  }
}

// =====================================================================
// res16 = normApply(h) @ c5_Wres(176x16) + c5_b   (norm+relu fused in load)
// =====================================================================
__global__ __launch_bounds__(256) void res16_kernel(const float* __restrict__ h,
                                                    const float* __restrict__ scsh,
                                                    const int* __restrict__ batch,
                                                    const float* __restrict__ Wres,
                                                    const float* __restrict__ b16,
                                                    float* __restrict__ res16) {
  __shared__ float Ws[176 * 16];
  __shared__ float hs[16 * 176];
  int t = threadIdx.x;
  for (int i = t; i < 176 * 16; i += 256) Ws[i] = Wres[i];
  int n0 = blockIdx.x * 16;
  for (int i = t; i < 16 * 176; i += 256) {
    int row = i / 176, k = i - row * 176;
    int g = batch[n0 + row];
    float v = h[(size_t)n0 * HC + i];
    hs[i] = fmaxf(fmaf(v, scsh[g * HC + k], scsh[(NGRAPH + g) * HC + k]), 0.0f);
  }
  __syncthreads();
  int tx = t & 15, ty = t >> 4;
  float acc = b16[tx];
  for (int k = 0; k < HC; k++) acc = fmaf(hs[ty * HC + k], Ws[k * 16 + tx], acc);
  res16[(size_t)(n0 + ty) * 16 + tx] = acc;
}

// =====================================================================
// Head MLP
// =====================================================================
__global__ __launch_bounds__(256) void head_kernel(
    const float* __restrict__ in16, const float* __restrict__ Wo1,
    const float* __restrict__ bo1, const float* __restrict__ Wo2,
    const float* __restrict__ bo2, const float* __restrict__ Wc,
    const float* __restrict__ bc, float* __restrict__ outp) {
  __shared__ float w1[256], w2[512], wcS[320], b1[16], b2[32], bcS[10];
  int t = threadIdx.x;
  for (int i = t; i < 256; i += 256) w1[i] = Wo1[i];
  for (int i = t; i < 512; i += 256) w2[i] = Wo2[i];
  for (int i = t; i < 320; i += 256) wcS[i] = Wc[i];
  if (t < 16) b1[t] = bo1[t];
  if (t < 32) b2[t] = bo2[t];
  if (t < 10) bcS[t] = bc[t];
  __syncthreads();
  int n = blockIdx.x * 256 + t;
  if (n >= N_NODES) return;
  float x[16];
#pragma unroll
  for (int i = 0; i < 16; i++) x[i] = in16[(size_t)n * 16 + i];
  float o1[16];
#pragma unroll
  for (int j = 0; j < 16; j++) {
    float a = b1[j];
#pragma unroll
    for (int k = 0; k < 16; k++) a = fmaf(x[k], w1[k * 16 + j], a);
    o1[j] = fmaxf(a, 0.0f);
  }
  float o2[32];
#pragma unroll
  for (int j = 0; j < 32; j++) {
    float a = b2[j];
#pragma unroll
    for (int k = 0; k < 16; k++) a = fmaf(o1[k], w2[k * 32 + j], a);
    o2[j] = fmaxf(a, 0.0f);
  }
#pragma unroll
  for (int j = 0; j < 10; j++) {
    float a = bcS[j];
#pragma unroll
    for (int k = 0; k < 32; k++) a = fmaf(o2[k], wcS[k * 10 + j], a);
    outp[(size_t)n * 10 + j] = a;
  }
}

// =====================================================================
extern "C" void kernel_launch(void* const* d_in, const int* in_sizes, int n_in,
                              void* d_out, int out_size, void* d_ws, size_t ws_size,
                              hipStream_t stream) {
  (void)in_sizes; (void)n_in; (void)out_size; (void)ws_size;
  const float* x     = (const float*)d_in[0];
  const int*   ei    = (const int*)d_in[1];
  const int*   srcE  = ei;
  const int*   dstE  = ei + N_EDGES;
  const int*   batch = (const int*)d_in[2];
  const float* W_pre = (const float*)d_in[3];
  const float* b_pre = (const float*)d_in[4];
  const float* gn_w  = (const float*)d_in[5];
  const float* gn_b  = (const float*)d_in[6];
  const float* gn_ms = (const float*)d_in[7];
  const float* cWl   = (const float*)d_in[8];
  const float* cWr   = (const float*)d_in[9];
  const float* cAtt  = (const float*)d_in[10];
  const float* cB    = (const float*)d_in[11];
  const float* cWres = (const float*)d_in[12];
  const float* c5Wl  = (const float*)d_in[13];
  const float* c5Wr  = (const float*)d_in[14];
  const float* c5Att = (const float*)d_in[15];
  const float* c5b   = (const float*)d_in[16];
  const float* c5Wres= (const float*)d_in[17];
  const float* Wo1   = (const float*)d_in[18];
  const float* bo1   = (const float*)d_in[19];
  const float* Wo2   = (const float*)d_in[20];
  const float* bo2   = (const float*)d_in[21];
  const float* Wc    = (const float*)d_in[22];
  const float* bc    = (const float*)d_in[23];

  const size_t FB = (size_t)N_NODES * HC;
  const size_t STB = (size_t)2 * NGRAPH * HC;  // one stats buffer (22528 floats)
  const size_t PB = (size_t)NBLK_ATTN * HC;    // 2.2M floats per partial array
  float* ws    = (float*)d_ws;
  float* buf0  = ws;
  float* buf1  = ws + FB;
  float* buf2  = ws + 2 * FB;
  float* buf3  = ws + 3 * FB;
  float* res16 = ws + 4 * FB;
  float* out16 = res16 + (size_t)N_NODES * 16;
  float* stats = out16 + (size_t)N_NODES * 16;         // 5 buffers (zeroed)
  int* deg     = (int*)(stats + 5 * STB);              // zeroed with stats
  int* fill    = deg + N_NODES;                        // zeroed with stats
  float* scsh  = (float*)(fill + N_NODES);
  float* parts = scsh + STB;
  float* partq = parts + PB;
  _Float16* wph = (_Float16*)(partq + PB);             // 991232 halves
  int* ibase   = (int*)((char*)wph + (size_t)991232 * 2);
  int* cntInt  = ibase;
  int* gstart  = ibase + 64;                           // 65 ints
  int* rowptr  = gstart + 65;
  int* colA    = rowptr + N_NODES + 1;
  int* bsum    = colA + N_EDGES;

  const int NB = (N_NODES + 255) / 256;

  // single memset: 5 stats buffers + deg + fill (contiguous)
  hipMemsetAsync(stats, 0, sizeof(float) * 5 * STB + sizeof(int) * 2 * N_NODES, stream);

  prep_kernel<<<(TOT_PAIRS + 255) / 256, 256, 0, stream>>>(W_pre, cWl, cWr, cWres, c5Wl, c5Wr, wph);
  cnt_bsearch_kernel<<<1, 64, 0, stream>>>(batch, cntInt, gstart);
  deg_hist_kernel<<<(N_EDGES + 255) / 256, 256, 0, stream>>>(dstE, deg);
  scan1_kernel<<<NB, 256, 0, stream>>>(deg, bsum);
  scan2_kernel<<<1, 256, 0, stream>>>(bsum, NB);
  scan3_kernel<<<NB, 256, 0, stream>>>(deg, bsum, rowptr);
  scatter_kernel<<<(N_EDGES + 255) / 256, 256, 0, stream>>>(srcE, dstE, rowptr, fill, colA);

  const int PRB = (NGRAPH * NCHUNK * HC + 255) / 256;  // 704 blocks for part_reduce

  // pre: buf0 = x @ W_pre + b_pre, with fused layer-0 GraphNorm partials
  gemm_mfma_t<2, true><<<GX8 * 1 * 8, 256, 0, stream>>>(
      x, N_NODES, IN_F, 4, 1, wph, 0, nullptr, batch,
      b_pre, nullptr, nullptr, buf0, nullptr, nullptr,
      parts, partq, stats);
  part_reduce_kernel<<<PRB, 256, 0, stream>>>(parts, partq, gstart, stats, 128);
  gn_finalize_kernel<<<(NGRAPH * HC + 255) / 256, 256, 0, stream>>>(stats, cntInt, gn_w, gn_b, gn_ms, 0, scsh);

  float* h = buf0;  // raw buffer; norm applied on the fly by consumers
  float* o = buf3;
  for (int i = 0; i < 4; i++) {
    const _Float16* Wcat_i = wph + PREH + (size_t)(3 * i) * MATH;
    gemm_mfma_t<3, false><<<GX8 * 3 * 8, 256, 0, stream>>>(
        h, N_NODES, HC, 6, 3, Wcat_i, MATH, scsh, batch,
        nullptr, nullptr, cB + i * HC, buf1, buf2, o,
        nullptr, nullptr, nullptr);
    float* st = stats + (size_t)(i + 1) * STB;
    attn_concat_kernel<<<NBLK_ATTN, 256, 0, stream>>>(buf1, buf2, cAtt + i * HC,
                                                      rowptr, colA, o, batch, st,
                                                      parts, partq);
    part_reduce_kernel<<<PRB, 256, 0, stream>>>(parts, partq, gstart, st, 4);
    gn_finalize_kernel<<<(NGRAPH * HC + 255) / 256, 256, 0, stream>>>(st, cntInt, gn_w, gn_b, gn_ms, i + 1, scsh);
    float* tmp = h; h = o; o = tmp;
  }

  // conv5 (input = raw h with scsh row 4 fused in consumers)
  const _Float16* Wc5 = wph + PREH + (size_t)12 * MATH;
  gemm_mfma_t<3, false><<<GX8 * 2 * 8, 256, 0, stream>>>(
      h, N_NODES, HC, 6, 2, Wc5, MATH, scsh, batch,
      nullptr, nullptr, nullptr, buf1, buf2, nullptr,
      nullptr, nullptr, nullptr);
  res16_kernel<<<N_NODES / 16, 256, 0, stream>>>(h, scsh, batch, c5Wres, c5b, res16);
  attn_mean_kernel<<<(N_NODES + 3) / 4, 256, 0, stream>>>(buf1, buf2, c5Att, rowptr, colA, res16, out16);

  head_kernel<<<NB, 256, 0, stream>>>(out16, Wo1, bo1, Wo2, bo2, Wc, bc, (float*)d_out);
}